// Round 2
// baseline (7398.013 us; speedup 1.0000x reference)
//
#include <hip/hip_runtime.h>
#include <cstdint>

typedef __attribute__((ext_vector_type(4))) float f32x4;
typedef __attribute__((ext_vector_type(8))) short s16x8;
typedef __attribute__((ext_vector_type(8))) unsigned short u16x8;
typedef __attribute__((ext_vector_type(4))) unsigned short u16x4;

#define DEVI __device__ __forceinline__

namespace {

constexpr int B = 32, L = 2048, D = 1024, H = 16;
constexpr int CHUNK = 128, MEM = 64, T = 192;
constexpr int NC = 16;

DEVI unsigned short f2bf(float f) {
  unsigned x = __builtin_bit_cast(unsigned, f);
  return (unsigned short)((x + 0x7fffu + ((x >> 16) & 1u)) >> 16);
}

typedef const __attribute__((address_space(1))) unsigned char ga_t;
typedef __attribute__((address_space(3))) unsigned char la_t;

DEVI void gload16(const void* g, void* l) {
  __builtin_amdgcn_global_load_lds((ga_t*)g, (la_t*)l, 16, 0, 0);
}

__global__ void k_cvt(const float* __restrict__ in, unsigned short* __restrict__ out, int n) {
  int i = blockIdx.x * 256 + threadIdx.x;
  if (i < n) out[i] = f2bf(in[i]);
}

__global__ void k_copy_mem(const float* __restrict__ src, float* __restrict__ dst) {
  int i = blockIdx.x * 256 + threadIdx.x;
  dst[i] = src[i];
}

// MODE 0: build z (mem/emb + pos), write z f32 and LN(z)->bf16
// MODE 1: read z f32, write LN(z)->bf16
template<int MODE>
__global__ __launch_bounds__(256) void k_ln(
    const float* __restrict__ memb, const float* __restrict__ mem_init,
    const float* __restrict__ pos,
    const float* __restrict__ embP, const float* __restrict__ embS,
    const int* __restrict__ ipr, const int* __restrict__ isk,
    const float* __restrict__ gg, const float* __restrict__ bb,
    float* __restrict__ z, unsigned short* __restrict__ lnout, int t)
{
  const int row = blockIdx.x;          // 0 .. B*T-1
  const int b = row / T, i = row % T;
  const int tid = threadIdx.x;
  const int d0 = tid * 4;
  float v[4];
  if constexpr (MODE == 0) {
    if (i < MEM) {
      const float* src = (t == 0) ? (mem_init + (size_t)i * D)
                                  : (memb + ((size_t)b * MEM + i) * D);
      #pragma unroll
      for (int e = 0; e < 4; ++e) v[e] = src[d0 + e] + pos[i * D + d0 + e];
    } else {
      const int j = t * CHUNK + (i - MEM);
      const int pi = ipr[b * L + j], si = isk[b * L + j];
      #pragma unroll
      for (int e = 0; e < 4; ++e)
        v[e] = embP[(size_t)pi * D + d0 + e] + embS[(size_t)si * D + d0 + e] + pos[i * D + d0 + e];
    }
  } else {
    const f32x4 zz = *reinterpret_cast<const f32x4*>(&z[(size_t)row * D + d0]);
    v[0] = zz[0]; v[1] = zz[1]; v[2] = zz[2]; v[3] = zz[3];
  }
  float s  = v[0] + v[1] + v[2] + v[3];
  float s2 = v[0]*v[0] + v[1]*v[1] + v[2]*v[2] + v[3]*v[3];
  #pragma unroll
  for (int m = 1; m < 64; m <<= 1) { s += __shfl_xor(s, m, 64); s2 += __shfl_xor(s2, m, 64); }
  __shared__ float ps[4], ps2[4];
  const int wid = tid >> 6;
  if ((tid & 63) == 0) { ps[wid] = s; ps2[wid] = s2; }
  __syncthreads();
  s  = ps[0] + ps[1] + ps[2] + ps[3];
  s2 = ps2[0] + ps2[1] + ps2[2] + ps2[3];
  const float mu  = s * (1.0f / 1024.0f);
  const float var = s2 * (1.0f / 1024.0f) - mu * mu;
  const float rs  = rsqrtf(var + 1e-5f);
  if constexpr (MODE == 0) {
    f32x4 zz = {v[0], v[1], v[2], v[3]};
    *reinterpret_cast<f32x4*>(&z[(size_t)row * D + d0]) = zz;
  }
  u16x4 o;
  #pragma unroll
  for (int e = 0; e < 4; ++e)
    o[e] = f2bf((v[e] - mu) * rs * gg[d0 + e] + bb[d0 + e]);
  *reinterpret_cast<u16x4*>(&lnout[(size_t)row * D + d0]) = o;
}

struct GArgs {
  const unsigned short* A; const unsigned short* W; const float* bias;
  unsigned short* outb; float* z; float* outf; unsigned short* candb; float* mem;
  int M, N, K, t;
};

// ---- legacy 128x128 kernel (kept for the small gate GEMM) ----
template<int EPI>
__global__ __launch_bounds__(256) void k_gemm(GArgs a)
{
  __shared__ unsigned short Al[128 * 64];
  __shared__ unsigned short Bl[128 * 64];
  const int tid = threadIdx.x;
  const int lane = tid & 63, wid = tid >> 6;
  const int brow = blockIdx.y * 128, bcol = blockIdx.x * 128;
  const int wr = wid >> 1, wc = wid & 1;
  const int lr = lane >> 3, lc8 = (lane & 7) * 8;
  const int c0 = lane & 15, g4 = lane >> 4;

  f32x4 acc[4][4] = {};

  const int nkt = a.K >> 6;
  for (int kt = 0; kt < nkt; ++kt) {
    const int kb = kt * 64;
    #pragma unroll
    for (int q = 0; q < 4; ++q) {
      const int seg = wid * 4 + q;                       // 0..15, 8 rows each
      gload16(&a.A[(size_t)(brow + seg * 8 + lr) * a.K + kb + lc8], &Al[seg * 512]);
      gload16(&a.W[(size_t)(bcol + seg * 8 + lr) * a.K + kb + lc8], &Bl[seg * 512]);
    }
    __syncthreads();
    #pragma unroll
    for (int kk = 0; kk < 2; ++kk) {
      s16x8 af[4], bf[4];
      #pragma unroll
      for (int m = 0; m < 4; ++m)
        af[m] = *reinterpret_cast<const s16x8*>(&Al[(wr * 64 + m * 16 + c0) * 64 + kk * 32 + g4 * 8]);
      #pragma unroll
      for (int n = 0; n < 4; ++n)
        bf[n] = *reinterpret_cast<const s16x8*>(&Bl[(wc * 64 + n * 16 + c0) * 64 + kk * 32 + g4 * 8]);
      #pragma unroll
      for (int m = 0; m < 4; ++m)
        #pragma unroll
        for (int n = 0; n < 4; ++n)
          acc[m][n] = __builtin_amdgcn_mfma_f32_16x16x32_bf16(af[m], bf[n], acc[m][n], 0, 0, 0);
    }
    __syncthreads();
  }

  #pragma unroll
  for (int m = 0; m < 4; ++m) {
    #pragma unroll
    for (int n = 0; n < 4; ++n) {
      const int col = bcol + wc * 64 + n * 16 + c0;
      const float bv = a.bias[col];
      #pragma unroll
      for (int j = 0; j < 4; ++j) {
        const int row = brow + wr * 64 + m * 16 + g4 * 4 + j;
        float v = acc[m][n][j] + bv;
        if constexpr (EPI == 0) {
          a.outb[(size_t)row * a.N + col] = f2bf(v);
        } else if constexpr (EPI == 1) {
          a.outb[(size_t)row * a.N + col] = f2bf(v > 0.f ? v : 0.f);
        } else if constexpr (EPI == 2) {
          a.z[(size_t)row * a.N + col] += v;
        } else if constexpr (EPI == 3) {
          const float zv = a.z[(size_t)row * a.N + col] + v;
          const int bb2 = row / T, ii = row % T;
          if (ii < MEM) {
            a.z[(size_t)row * a.N + col] = zv;
            a.candb[((size_t)bb2 * MEM + ii) * D + col] = f2bf(zv);
          } else {
            a.outf[((size_t)bb2 * L + a.t * CHUNK + (ii - MEM)) * D + col] = zv;
          }
        } else {
          const float g = 1.0f / (1.0f + __expf(-v));
          const int bb2 = row >> 6, ii = row & 63;
          const float cand = a.z[((size_t)bb2 * T + ii) * D + col];
          const float mo = a.mem[(size_t)row * D + col];
          a.mem[(size_t)row * D + col] = (a.t == 0) ? cand : g * cand + (1.0f - g) * mo;
        }
      }
    }
  }
}

// ---- 256x128-tile 8-wave pipelined GEMM (T2 swizzle + T4 counted vmcnt + T5) ----
// Per K-tile (64), two phases (K-halves of 32). Each phase:
//   stage next tile's same K-half (3 x global_load_lds, pre-swizzled source)
//   10 x ds_read_b128 (swizzled), 16 MFMA under setprio, vmcnt(3)+barrier.
// Certification lag = 2 phases; vmcnt never drains to 0 except at the last tile.
template<int EPI>
__global__ __launch_bounds__(512, 2) void k_gemm2(GArgs a)
{
  __shared__ __align__(16) unsigned short AL[2][2][256 * 32];
  __shared__ __align__(16) unsigned short BL[2][2][128 * 32];
  const int tid = threadIdx.x;
  const int lane = tid & 63, wid = tid >> 6;
  const int c0 = lane & 15, g4 = lane >> 4;
  const int wr = wid >> 2, wcv = wid & 3;
  const int brow = blockIdx.y * 256, bcol = blockIdx.x * 128;
  const int K = a.K;
  const int nt = K >> 6;

  f32x4 acc[8][2] = {};

  // staging: thread u covers (row r = u>>2, 16B slot s = u&3); slot s of row r
  // holds k-octet g = s ^ (r&3)  (XOR involution, applied on the global source)
  const int r0 = tid >> 2, s0 = tid & 3;
  const int gsw = (s0 ^ (r0 & 3)) * 8;     // element offset within the 32-k half
  const int ldsA0 = wid * 512, ldsA1 = (wid + 8) * 512, ldsB0 = wid * 512;
  // read side: my k-octet g4 lives at slot g4 ^ (row&3); row&3 == c0&3 here
  const int slotE = (g4 ^ (c0 & 3)) * 8;

  const unsigned short* __restrict__ Ag = a.A;
  const unsigned short* __restrict__ Wg = a.W;

  auto stage = [&](int t1, int kh) {
    const int q = t1 & 1;
    const size_t kc = (size_t)t1 * 64 + kh * 32 + gsw;
    gload16(&Ag[(size_t)(brow + r0) * K + kc],       &AL[q][kh][ldsA0]);
    gload16(&Ag[(size_t)(brow + 128 + r0) * K + kc], &AL[q][kh][ldsA1]);
    gload16(&Wg[(size_t)(bcol + r0) * K + kc],       &BL[q][kh][ldsB0]);
  };

  // prologue: tile 0 fully staged + certified
  stage(0, 0); stage(0, 1);
  asm volatile("s_waitcnt vmcnt(0)" ::: "memory");
  __builtin_amdgcn_s_barrier();
  asm volatile("" ::: "memory");

  for (int t = 0; t < nt; ++t) {
    const int p = t & 1;
    #pragma unroll
    for (int kh = 0; kh < 2; ++kh) {
      if (t + 1 < nt) stage(t + 1, kh);
      const unsigned short* Ah = &AL[p][kh][0];
      const unsigned short* Bh = &BL[p][kh][0];
      s16x8 af[8], bf[2];
      #pragma unroll
      for (int m = 0; m < 8; ++m)
        af[m] = *reinterpret_cast<const s16x8*>(&Ah[(wr * 128 + m * 16 + c0) * 32 + slotE]);
      #pragma unroll
      for (int n = 0; n < 2; ++n)
        bf[n] = *reinterpret_cast<const s16x8*>(&Bh[(wcv * 32 + n * 16 + c0) * 32 + slotE]);
      __builtin_amdgcn_s_setprio(1);
      #pragma unroll
      for (int m = 0; m < 8; ++m)
        #pragma unroll
        for (int n = 0; n < 2; ++n)
          acc[m][n] = __builtin_amdgcn_mfma_f32_16x16x32_bf16(af[m], bf[n], acc[m][n], 0, 0, 0);
      __builtin_amdgcn_s_setprio(0);
      if (t + 1 < nt) { asm volatile("s_waitcnt vmcnt(3)" ::: "memory"); }
      else            { asm volatile("s_waitcnt vmcnt(0)" ::: "memory"); }
      __builtin_amdgcn_s_barrier();
      asm volatile("" ::: "memory");
    }
  }

  #pragma unroll
  for (int m = 0; m < 8; ++m) {
    #pragma unroll
    for (int n = 0; n < 2; ++n) {
      const int col = bcol + wcv * 32 + n * 16 + c0;
      const float bv = a.bias[col];
      #pragma unroll
      for (int j = 0; j < 4; ++j) {
        const int row = brow + wr * 128 + m * 16 + g4 * 4 + j;
        float v = acc[m][n][j] + bv;
        if constexpr (EPI == 0) {
          a.outb[(size_t)row * a.N + col] = f2bf(v);
        } else if constexpr (EPI == 1) {
          a.outb[(size_t)row * a.N + col] = f2bf(v > 0.f ? v : 0.f);
        } else if constexpr (EPI == 2) {
          a.z[(size_t)row * a.N + col] += v;
        } else if constexpr (EPI == 3) {
          const float zv = a.z[(size_t)row * a.N + col] + v;
          const int bb2 = row / T, ii = row % T;
          if (ii < MEM) {
            a.z[(size_t)row * a.N + col] = zv;
            a.candb[((size_t)bb2 * MEM + ii) * D + col] = f2bf(zv);
          } else {
            a.outf[((size_t)bb2 * L + a.t * CHUNK + (ii - MEM)) * D + col] = zv;
          }
        }
      }
    }
  }
}

// One workgroup per (b,h). qkv: [B*T][3072] bf16 (q|k|v each H*64 cols).
__global__ __launch_bounds__(256) void k_attn(const unsigned short* __restrict__ qkv,
                                              unsigned short* __restrict__ attno)
{
  __shared__ unsigned short Ks[192 * 64];    // K, 8-elem-block XOR swizzle
  __shared__ unsigned short Vt[64 * 192];    // V^T, 8-key-block rotation per hd row
  __shared__ unsigned short Pl[4][16 * 200]; // per-wave P, padded rows
  const int tid = threadIdx.x, lane = tid & 63, wid = tid >> 6;
  const int b = blockIdx.x >> 4, h = blockIdx.x & 15;
  const size_t base = (size_t)b * T * 3072 + h * 64;

  #pragma unroll
  for (int it = 0; it < 6; ++it) {
    const int cidx = tid + it * 256;         // 0..1535 = 192 keys * 8 blocks
    const int key = cidx >> 3, hb = cidx & 7;
    const u16x8 kv = *reinterpret_cast<const u16x8*>(&qkv[base + (size_t)key * 3072 + 1024 + hb * 8]);
    *reinterpret_cast<u16x8*>(&Ks[key * 64 + ((hb ^ (key & 7)) * 8)]) = kv;
    const u16x8 vv = *reinterpret_cast<const u16x8*>(&qkv[base + (size_t)key * 3072 + 2048 + hb * 8]);
    #pragma unroll
    for (int e = 0; e < 8; ++e) {
      const int hd = hb * 8 + e;
      Vt[hd * 192 + (((key >> 3) + hd) % 24) * 8 + (key & 7)] = vv[e];
    }
  }
  __syncthreads();

  const int c0 = lane & 15, g4 = lane >> 4;
  for (int qb = wid; qb < 12; qb += 4) {     // 3 q-blocks per wave
    s16x8 qf[2];
    #pragma unroll
    for (int kk = 0; kk < 2; ++kk)
      qf[kk] = *reinterpret_cast<const s16x8*>(&qkv[base + (size_t)(qb * 16 + c0) * 3072 + kk * 32 + g4 * 8]);
    f32x4 sc[12];
    #pragma unroll
    for (int cb = 0; cb < 12; ++cb) {
      f32x4 s4 = {};
      #pragma unroll
      for (int kk = 0; kk < 2; ++kk) {
        const s16x8 kf = *reinterpret_cast<const s16x8*>(
            &Ks[(cb * 16 + c0) * 64 + (((kk * 4 + g4) ^ (c0 & 7)) * 8)]);
        s4 = __builtin_amdgcn_mfma_f32_16x16x32_bf16(qf[kk], kf, s4, 0, 0, 0);
      }
      sc[cb] = s4;
    }
    #pragma unroll
    for (int j = 0; j < 4; ++j) {
      const int qi = qb * 16 + g4 * 4 + j;
      float mj = -1e30f;
      #pragma unroll
      for (int cb = 0; cb < 12; ++cb) {
        const int kj = cb * 16 + c0;
        float sv = sc[cb][j] * 0.125f;
        if (qi >= MEM && kj > qi) sv = -1e30f;
        sc[cb][j] = sv;
        mj = fmaxf(mj, sv);
      }
      #pragma unroll
      for (int msk = 1; msk <= 8; msk <<= 1) mj = fmaxf(mj, __shfl_xor(mj, msk, 64));
      float sum = 0.f;
      #pragma unroll
      for (int cb = 0; cb < 12; ++cb) {
        const float p = exp2f((sc[cb][j] - mj) * 1.44269504f);
        sc[cb][j] = p;
        sum += p;
      }
      #pragma unroll
      for (int msk = 1; msk <= 8; msk <<= 1) sum += __shfl_xor(sum, msk, 64);
      const float rin = 1.0f / sum;
      #pragma unroll
      for (int cb = 0; cb < 12; ++cb)
        Pl[wid][(g4 * 4 + j) * 200 + cb * 16 + c0] = f2bf(sc[cb][j] * rin);
    }
    #pragma unroll
    for (int cb2 = 0; cb2 < 4; ++cb2) {
      f32x4 ao = {};
      const int hd = cb2 * 16 + c0;
      #pragma unroll
      for (int kk = 0; kk < 6; ++kk) {
        const int k0 = kk * 32 + g4 * 8;
        const s16x8 pf = *reinterpret_cast<const s16x8*>(&Pl[wid][c0 * 200 + k0]);
        const s16x8 vf = *reinterpret_cast<const s16x8*>(&Vt[hd * 192 + (((k0 >> 3) + hd) % 24) * 8]);
        ao = __builtin_amdgcn_mfma_f32_16x16x32_bf16(pf, vf, ao, 0, 0, 0);
      }
      #pragma unroll
      for (int j = 0; j < 4; ++j) {
        const int q = qb * 16 + g4 * 4 + j;
        attno[((size_t)b * T + q) * D + h * 64 + cb2 * 16 + c0] = f2bf(ao[j]);
      }
    }
  }
}

} // namespace

extern "C" void kernel_launch(void* const* d_in, const int* in_sizes, int n_in,
                              void* d_out, int out_size, void* d_ws, size_t ws_size,
                              hipStream_t stream)
{
  const int*   ipr      = (const int*)d_in[0];
  const int*   isk      = (const int*)d_in[1];
  const float* embP     = (const float*)d_in[2];
  const float* embS     = (const float*)d_in[3];
  const float* mem_init = (const float*)d_in[4];
  const float* pos      = (const float*)d_in[5];
  const float* wqkv     = (const float*)d_in[6];
  const float* bqkv     = (const float*)d_in[7];
  const float* wo       = (const float*)d_in[8];
  const float* bo       = (const float*)d_in[9];
  const float* w1       = (const float*)d_in[10];
  const float* b1       = (const float*)d_in[11];
  const float* w2       = (const float*)d_in[12];
  const float* b2       = (const float*)d_in[13];
  const float* ln_a_g   = (const float*)d_in[14];
  const float* ln_a_b   = (const float*)d_in[15];
  const float* ln_f_g   = (const float*)d_in[16];
  const float* ln_f_b   = (const float*)d_in[17];
  const float* gw       = (const float*)d_in[18];
  const float* gb       = (const float*)d_in[19];
  float* out = (float*)d_out;
  (void)in_sizes; (void)n_in; (void)out_size; (void)ws_size;

  char* ws = (char*)d_ws;
  size_t off = 0;
  auto alloc = [&](size_t bytes) -> void* {
    void* p = ws + off; off += (bytes + 255) & ~(size_t)255; return p;
  };
  unsigned short* wqkv_b = (unsigned short*)alloc((size_t)3072 * 1024 * 2);
  unsigned short* wo_b   = (unsigned short*)alloc((size_t)1024 * 1024 * 2);
  unsigned short* w1_b   = (unsigned short*)alloc((size_t)4096 * 1024 * 2);
  unsigned short* w2_b   = (unsigned short*)alloc((size_t)1024 * 4096 * 2);
  unsigned short* gw_b   = (unsigned short*)alloc((size_t)1024 * 1024 * 2);
  float*          z      = (float*)alloc((size_t)B * T * D * 4);
  unsigned short* lnb    = (unsigned short*)alloc((size_t)B * T * D * 2);
  unsigned short* atno   = (unsigned short*)alloc((size_t)B * T * D * 2);
  unsigned short* big    = (unsigned short*)alloc((size_t)B * T * 4096 * 2); // qkv then ffn1
  unsigned short* candb  = (unsigned short*)alloc((size_t)B * MEM * D * 2);
  float*          memb   = (float*)alloc((size_t)B * MEM * D * 4);

  k_cvt<<<(3072 * 1024) / 256, 256, 0, stream>>>(wqkv, wqkv_b, 3072 * 1024);
  k_cvt<<<(1024 * 1024) / 256, 256, 0, stream>>>(wo,   wo_b,   1024 * 1024);
  k_cvt<<<(4096 * 1024) / 256, 256, 0, stream>>>(w1,   w1_b,   4096 * 1024);
  k_cvt<<<(1024 * 4096) / 256, 256, 0, stream>>>(w2,   w2_b,   1024 * 4096);
  k_cvt<<<(1024 * 1024) / 256, 256, 0, stream>>>(gw,   gw_b,   1024 * 1024);

  for (int t = 0; t < NC; ++t) {
    k_ln<0><<<B * T, 256, 0, stream>>>(memb, mem_init, pos, embP, embS, ipr, isk,
                                       ln_a_g, ln_a_b, z, lnb, t);
    { GArgs a{lnb, wqkv_b, bqkv, big, nullptr, nullptr, nullptr, nullptr, B * T, 3072, 1024, t};
      k_gemm2<0><<<dim3(3072 / 128, (B * T) / 256), 512, 0, stream>>>(a); }
    k_attn<<<B * H, 256, 0, stream>>>(big, atno);
    { GArgs a{atno, wo_b, bo, nullptr, z, nullptr, nullptr, nullptr, B * T, 1024, 1024, t};
      k_gemm2<2><<<dim3(1024 / 128, (B * T) / 256), 512, 0, stream>>>(a); }
    k_ln<1><<<B * T, 256, 0, stream>>>(nullptr, nullptr, nullptr, nullptr, nullptr,
                                       nullptr, nullptr, ln_f_g, ln_f_b, z, lnb, t);
    { GArgs a{lnb, w1_b, b1, big, nullptr, nullptr, nullptr, nullptr, B * T, 4096, 1024, t};
      k_gemm2<1><<<dim3(4096 / 128, (B * T) / 256), 512, 0, stream>>>(a); }
    { GArgs a{big, w2_b, b2, nullptr, z, out, candb, nullptr, B * T, 1024, 4096, t};
      k_gemm2<3><<<dim3(1024 / 128, (B * T) / 256), 512, 0, stream>>>(a); }
    { GArgs a{candb, gw_b, gb, nullptr, z, nullptr, nullptr, memb, B * MEM, 1024, 1024, t};
      k_gemm<4><<<dim3(1024 / 128, (B * MEM) / 128), 256, 0, stream>>>(a); }
  }
  k_copy_mem<<<(B * MEM * D) / 256, 256, 0, stream>>>(memb, out + (size_t)B * L * D);
}

// Round 3
// 6796.503 us; speedup vs baseline: 1.0885x; 1.0885x over previous
//
#include <hip/hip_runtime.h>
#include <cstdint>

typedef __attribute__((ext_vector_type(4))) float f32x4;
typedef __attribute__((ext_vector_type(8))) short s16x8;
typedef __attribute__((ext_vector_type(8))) unsigned short u16x8;
typedef __attribute__((ext_vector_type(4))) unsigned short u16x4;

#define DEVI __device__ __forceinline__

namespace {

constexpr int B = 32, L = 2048, D = 1024, H = 16;
constexpr int CHUNK = 128, MEM = 64, T = 192;
constexpr int NC = 16;

DEVI unsigned short f2bf(float f) {
  unsigned x = __builtin_bit_cast(unsigned, f);
  return (unsigned short)((x + 0x7fffu + ((x >> 16) & 1u)) >> 16);
}

typedef const __attribute__((address_space(1))) unsigned char ga_t;
typedef __attribute__((address_space(3))) unsigned char la_t;

DEVI void gload16(const void* g, void* l) {
  __builtin_amdgcn_global_load_lds((ga_t*)g, (la_t*)l, 16, 0, 0);
}

__global__ void k_cvt(const float* __restrict__ in, unsigned short* __restrict__ out, int n) {
  int i = blockIdx.x * 256 + threadIdx.x;
  if (i < n) out[i] = f2bf(in[i]);
}

__global__ void k_copy_mem(const float* __restrict__ src, float* __restrict__ dst) {
  int i = blockIdx.x * 256 + threadIdx.x;
  dst[i] = src[i];
}

// MODE 0: build z (mem/emb + pos), write z f32 and LN(z)->bf16
// MODE 1: read z f32, write LN(z)->bf16
template<int MODE>
__global__ __launch_bounds__(256) void k_ln(
    const float* __restrict__ memb, const float* __restrict__ mem_init,
    const float* __restrict__ pos,
    const float* __restrict__ embP, const float* __restrict__ embS,
    const int* __restrict__ ipr, const int* __restrict__ isk,
    const float* __restrict__ gg, const float* __restrict__ bb,
    float* __restrict__ z, unsigned short* __restrict__ lnout, int t)
{
  const int row = blockIdx.x;          // 0 .. B*T-1
  const int b = row / T, i = row % T;
  const int tid = threadIdx.x;
  const int d0 = tid * 4;
  float v[4];
  if constexpr (MODE == 0) {
    if (i < MEM) {
      const float* src = (t == 0) ? (mem_init + (size_t)i * D)
                                  : (memb + ((size_t)b * MEM + i) * D);
      #pragma unroll
      for (int e = 0; e < 4; ++e) v[e] = src[d0 + e] + pos[i * D + d0 + e];
    } else {
      const int j = t * CHUNK + (i - MEM);
      const int pi = ipr[b * L + j], si = isk[b * L + j];
      #pragma unroll
      for (int e = 0; e < 4; ++e)
        v[e] = embP[(size_t)pi * D + d0 + e] + embS[(size_t)si * D + d0 + e] + pos[i * D + d0 + e];
    }
  } else {
    const f32x4 zz = *reinterpret_cast<const f32x4*>(&z[(size_t)row * D + d0]);
    v[0] = zz[0]; v[1] = zz[1]; v[2] = zz[2]; v[3] = zz[3];
  }
  float s  = v[0] + v[1] + v[2] + v[3];
  float s2 = v[0]*v[0] + v[1]*v[1] + v[2]*v[2] + v[3]*v[3];
  #pragma unroll
  for (int m = 1; m < 64; m <<= 1) { s += __shfl_xor(s, m, 64); s2 += __shfl_xor(s2, m, 64); }
  __shared__ float ps[4], ps2[4];
  const int wid = tid >> 6;
  if ((tid & 63) == 0) { ps[wid] = s; ps2[wid] = s2; }
  __syncthreads();
  s  = ps[0] + ps[1] + ps[2] + ps[3];
  s2 = ps2[0] + ps2[1] + ps2[2] + ps2[3];
  const float mu  = s * (1.0f / 1024.0f);
  const float var = s2 * (1.0f / 1024.0f) - mu * mu;
  const float rs  = rsqrtf(var + 1e-5f);
  if constexpr (MODE == 0) {
    f32x4 zz = {v[0], v[1], v[2], v[3]};
    *reinterpret_cast<f32x4*>(&z[(size_t)row * D + d0]) = zz;
  }
  u16x4 o;
  #pragma unroll
  for (int e = 0; e < 4; ++e)
    o[e] = f2bf((v[e] - mu) * rs * gg[d0 + e] + bb[d0 + e]);
  *reinterpret_cast<u16x4*>(&lnout[(size_t)row * D + d0]) = o;
}

struct GArgs {
  const unsigned short* A; const unsigned short* W; const float* bias;
  unsigned short* outb; float* z; float* outf; unsigned short* candb; float* mem;
  int M, N, K, t;
};

// ---- legacy 128x128 kernel (kept for the small gate GEMM) ----
template<int EPI>
__global__ __launch_bounds__(256) void k_gemm(GArgs a)
{
  __shared__ unsigned short Al[128 * 64];
  __shared__ unsigned short Bl[128 * 64];
  const int tid = threadIdx.x;
  const int lane = tid & 63, wid = tid >> 6;
  const int brow = blockIdx.y * 128, bcol = blockIdx.x * 128;
  const int wr = wid >> 1, wc = wid & 1;
  const int lr = lane >> 3, lc8 = (lane & 7) * 8;
  const int c0 = lane & 15, g4 = lane >> 4;

  f32x4 acc[4][4] = {};

  const int nkt = a.K >> 6;
  for (int kt = 0; kt < nkt; ++kt) {
    const int kb = kt * 64;
    #pragma unroll
    for (int q = 0; q < 4; ++q) {
      const int seg = wid * 4 + q;
      gload16(&a.A[(size_t)(brow + seg * 8 + lr) * a.K + kb + lc8], &Al[seg * 512]);
      gload16(&a.W[(size_t)(bcol + seg * 8 + lr) * a.K + kb + lc8], &Bl[seg * 512]);
    }
    __syncthreads();
    #pragma unroll
    for (int kk = 0; kk < 2; ++kk) {
      s16x8 af[4], bf[4];
      #pragma unroll
      for (int m = 0; m < 4; ++m)
        af[m] = *reinterpret_cast<const s16x8*>(&Al[(wr * 64 + m * 16 + c0) * 64 + kk * 32 + g4 * 8]);
      #pragma unroll
      for (int n = 0; n < 4; ++n)
        bf[n] = *reinterpret_cast<const s16x8*>(&Bl[(wc * 64 + n * 16 + c0) * 64 + kk * 32 + g4 * 8]);
      #pragma unroll
      for (int m = 0; m < 4; ++m)
        #pragma unroll
        for (int n = 0; n < 4; ++n)
          acc[m][n] = __builtin_amdgcn_mfma_f32_16x16x32_bf16(af[m], bf[n], acc[m][n], 0, 0, 0);
    }
    __syncthreads();
  }

  #pragma unroll
  for (int m = 0; m < 4; ++m) {
    #pragma unroll
    for (int n = 0; n < 4; ++n) {
      const int col = bcol + wc * 64 + n * 16 + c0;
      const float bv = a.bias[col];
      #pragma unroll
      for (int j = 0; j < 4; ++j) {
        const int row = brow + wr * 64 + m * 16 + g4 * 4 + j;
        float v = acc[m][n][j] + bv;
        if constexpr (EPI == 0) {
          a.outb[(size_t)row * a.N + col] = f2bf(v);
        } else if constexpr (EPI == 1) {
          a.outb[(size_t)row * a.N + col] = f2bf(v > 0.f ? v : 0.f);
        } else if constexpr (EPI == 2) {
          a.z[(size_t)row * a.N + col] += v;
        } else if constexpr (EPI == 3) {
          const float zv = a.z[(size_t)row * a.N + col] + v;
          const int bb2 = row / T, ii = row % T;
          if (ii < MEM) {
            a.z[(size_t)row * a.N + col] = zv;
            a.candb[((size_t)bb2 * MEM + ii) * D + col] = f2bf(zv);
          } else {
            a.outf[((size_t)bb2 * L + a.t * CHUNK + (ii - MEM)) * D + col] = zv;
          }
        } else {
          const float g = 1.0f / (1.0f + __expf(-v));
          const int bb2 = row >> 6, ii = row & 63;
          const float cand = a.z[((size_t)bb2 * T + ii) * D + col];
          const float mo = a.mem[(size_t)row * D + col];
          a.mem[(size_t)row * D + col] = (a.t == 0) ? cand : g * cand + (1.0f - g) * mo;
        }
      }
    }
  }
}

// ---- 256x128-tile, 8-wave, TRIPLE-buffered pipelined GEMM ----
// Tile t is computed while tile t+1 is certified-resident and tile t+2 is in
// flight (issued during tile t, waited at end of tile t+1 => ~4-phase lag).
// vmcnt(6) at tile boundaries only; never drains to 0 in steady state (T4).
// Full 8-slot XOR swizzle (slot ^= row&7) => conflict-free ds_read_b128 (T2).
// 16 MFMA per phase under setprio (T5).
template<int EPI>
__global__ __launch_bounds__(512, 2) void k_gemm3(GArgs a)
{
  __shared__ __align__(16) unsigned short AL[3][256 * 64];  // 96 KB
  __shared__ __align__(16) unsigned short BL[3][128 * 64];  // 48 KB
  const int tid = threadIdx.x;
  const int lane = tid & 63, wid = tid >> 6;
  const int c0 = lane & 15, g4 = lane >> 4;
  const int wr = wid >> 1, wc = wid & 1;          // 4M x 2N waves, 64x64 out each
  const int brow = blockIdx.y * 256, bcol = blockIdx.x * 128;
  const int K = a.K;
  const int nt = K >> 6;

  f32x4 acc[4][4] = {};

  // staging geometry: each gload16 covers 64 rows (8 rows/wave), 8 slots/row.
  // LDS is linear [row][slot]; the global source k-octet is pre-XOR'd so that
  // LDS slot s of row r holds k-octet s^(r&7)  (both-sides involution).
  const int rloc = (wid << 3) + (lane >> 3);              // row within 64-block
  const int gko  = ((lane & 7) ^ (lane >> 3)) << 3;       // element k-offset
  const unsigned short* __restrict__ Ag = a.A;
  const unsigned short* __restrict__ Wg = a.W;

  auto stage = [&](int t1, int part) {
    const int q = t1 % 3;
    const size_t kc = (size_t)t1 * 64 + gko;
    gload16(&Ag[(size_t)(brow + part * 128      + rloc) * K + kc],
            &AL[q][(part * 128      + (wid << 3)) * 64]);
    gload16(&Ag[(size_t)(brow + part * 128 + 64 + rloc) * K + kc],
            &AL[q][(part * 128 + 64 + (wid << 3)) * 64]);
    gload16(&Wg[(size_t)(bcol + part * 64       + rloc) * K + kc],
            &BL[q][(part * 64       + (wid << 3)) * 64]);
  };

  // prologue: tiles 0 and 1 issued; certify tile 0 (vmcnt(6) leaves tile 1 in flight)
  stage(0, 0); stage(0, 1); stage(1, 0); stage(1, 1);
  asm volatile("s_waitcnt vmcnt(6)" ::: "memory");
  __builtin_amdgcn_s_barrier();

  for (int t = 0; t < nt; ++t) {
    const int q = t % 3;
    #pragma unroll
    for (int ks = 0; ks < 2; ++ks) {
      if (t + 2 < nt) stage(t + 2, ks);
      s16x8 af[4], bf[4];
      #pragma unroll
      for (int m = 0; m < 4; ++m)
        af[m] = *reinterpret_cast<const s16x8*>(
            &AL[q][(wr * 64 + m * 16 + c0) * 64 + (((ks * 4 + g4) ^ (c0 & 7)) << 3)]);
      #pragma unroll
      for (int n = 0; n < 4; ++n)
        bf[n] = *reinterpret_cast<const s16x8*>(
            &BL[q][(wc * 64 + n * 16 + c0) * 64 + (((ks * 4 + g4) ^ (c0 & 7)) << 3)]);
      __builtin_amdgcn_s_setprio(1);
      #pragma unroll
      for (int m = 0; m < 4; ++m)
        #pragma unroll
        for (int n = 0; n < 4; ++n)
          acc[m][n] = __builtin_amdgcn_mfma_f32_16x16x32_bf16(af[m], bf[n], acc[m][n], 0, 0, 0);
      __builtin_amdgcn_s_setprio(0);
      if (ks == 0) {
        __builtin_amdgcn_s_barrier();
      } else if (t + 1 < nt) {
        if (t + 2 < nt) { asm volatile("s_waitcnt vmcnt(6)" ::: "memory"); }
        else            { asm volatile("s_waitcnt vmcnt(0)" ::: "memory"); }
        __builtin_amdgcn_s_barrier();
      }
    }
  }

  #pragma unroll
  for (int m = 0; m < 4; ++m) {
    #pragma unroll
    for (int n = 0; n < 4; ++n) {
      const int col = bcol + wc * 64 + n * 16 + c0;
      const float bv = a.bias[col];
      #pragma unroll
      for (int j = 0; j < 4; ++j) {
        const int row = brow + wr * 64 + m * 16 + g4 * 4 + j;
        float v = acc[m][n][j] + bv;
        if constexpr (EPI == 0) {
          a.outb[(size_t)row * a.N + col] = f2bf(v);
        } else if constexpr (EPI == 1) {
          a.outb[(size_t)row * a.N + col] = f2bf(v > 0.f ? v : 0.f);
        } else if constexpr (EPI == 2) {
          a.z[(size_t)row * a.N + col] += v;
        } else if constexpr (EPI == 3) {
          const float zv = a.z[(size_t)row * a.N + col] + v;
          const int bb2 = row / T, ii = row % T;
          if (ii < MEM) {
            a.z[(size_t)row * a.N + col] = zv;
            a.candb[((size_t)bb2 * MEM + ii) * D + col] = f2bf(zv);
          } else {
            a.outf[((size_t)bb2 * L + a.t * CHUNK + (ii - MEM)) * D + col] = zv;
          }
        }
      }
    }
  }
}

// One workgroup per (b,h). qkv: [B*T][3072] bf16 (q|k|v each H*64 cols).
__global__ __launch_bounds__(256) void k_attn(const unsigned short* __restrict__ qkv,
                                              unsigned short* __restrict__ attno)
{
  __shared__ unsigned short Ks[192 * 64];    // K, 8-elem-block XOR swizzle
  __shared__ unsigned short Vt[64 * 192];    // V^T, 8-key-block rotation per hd row
  __shared__ unsigned short Pl[4][16 * 200]; // per-wave P, padded rows
  const int tid = threadIdx.x, lane = tid & 63, wid = tid >> 6;
  const int b = blockIdx.x >> 4, h = blockIdx.x & 15;
  const size_t base = (size_t)b * T * 3072 + h * 64;

  #pragma unroll
  for (int it = 0; it < 6; ++it) {
    const int cidx = tid + it * 256;         // 0..1535 = 192 keys * 8 blocks
    const int key = cidx >> 3, hb = cidx & 7;
    const u16x8 kv = *reinterpret_cast<const u16x8*>(&qkv[base + (size_t)key * 3072 + 1024 + hb * 8]);
    *reinterpret_cast<u16x8*>(&Ks[key * 64 + ((hb ^ (key & 7)) * 8)]) = kv;
    const u16x8 vv = *reinterpret_cast<const u16x8*>(&qkv[base + (size_t)key * 3072 + 2048 + hb * 8]);
    #pragma unroll
    for (int e = 0; e < 8; ++e) {
      const int hd = hb * 8 + e;
      Vt[hd * 192 + (((key >> 3) + hd) % 24) * 8 + (key & 7)] = vv[e];
    }
  }
  __syncthreads();

  const int c0 = lane & 15, g4 = lane >> 4;
  for (int qb = wid; qb < 12; qb += 4) {     // 3 q-blocks per wave
    s16x8 qf[2];
    #pragma unroll
    for (int kk = 0; kk < 2; ++kk)
      qf[kk] = *reinterpret_cast<const s16x8*>(&qkv[base + (size_t)(qb * 16 + c0) * 3072 + kk * 32 + g4 * 8]);
    f32x4 sc[12];
    #pragma unroll
    for (int cb = 0; cb < 12; ++cb) {
      f32x4 s4 = {};
      #pragma unroll
      for (int kk = 0; kk < 2; ++kk) {
        const s16x8 kf = *reinterpret_cast<const s16x8*>(
            &Ks[(cb * 16 + c0) * 64 + (((kk * 4 + g4) ^ (c0 & 7)) * 8)]);
        s4 = __builtin_amdgcn_mfma_f32_16x16x32_bf16(qf[kk], kf, s4, 0, 0, 0);
      }
      sc[cb] = s4;
    }
    #pragma unroll
    for (int j = 0; j < 4; ++j) {
      const int qi = qb * 16 + g4 * 4 + j;
      float mj = -1e30f;
      #pragma unroll
      for (int cb = 0; cb < 12; ++cb) {
        const int kj = cb * 16 + c0;
        float sv = sc[cb][j] * 0.125f;
        if (qi >= MEM && kj > qi) sv = -1e30f;
        sc[cb][j] = sv;
        mj = fmaxf(mj, sv);
      }
      #pragma unroll
      for (int msk = 1; msk <= 8; msk <<= 1) mj = fmaxf(mj, __shfl_xor(mj, msk, 64));
      float sum = 0.f;
      #pragma unroll
      for (int cb = 0; cb < 12; ++cb) {
        const float p = exp2f((sc[cb][j] - mj) * 1.44269504f);
        sc[cb][j] = p;
        sum += p;
      }
      #pragma unroll
      for (int msk = 1; msk <= 8; msk <<= 1) sum += __shfl_xor(sum, msk, 64);
      const float rin = 1.0f / sum;
      #pragma unroll
      for (int cb = 0; cb < 12; ++cb)
        Pl[wid][(g4 * 4 + j) * 200 + cb * 16 + c0] = f2bf(sc[cb][j] * rin);
    }
    #pragma unroll
    for (int cb2 = 0; cb2 < 4; ++cb2) {
      f32x4 ao = {};
      const int hd = cb2 * 16 + c0;
      #pragma unroll
      for (int kk = 0; kk < 6; ++kk) {
        const int k0 = kk * 32 + g4 * 8;
        const s16x8 pf = *reinterpret_cast<const s16x8*>(&Pl[wid][c0 * 200 + k0]);
        const s16x8 vf = *reinterpret_cast<const s16x8*>(&Vt[hd * 192 + (((k0 >> 3) + hd) % 24) * 8]);
        ao = __builtin_amdgcn_mfma_f32_16x16x32_bf16(pf, vf, ao, 0, 0, 0);
      }
      #pragma unroll
      for (int j = 0; j < 4; ++j) {
        const int q = qb * 16 + g4 * 4 + j;
        attno[((size_t)b * T + q) * D + h * 64 + cb2 * 16 + c0] = f2bf(ao[j]);
      }
    }
  }
}

} // namespace

extern "C" void kernel_launch(void* const* d_in, const int* in_sizes, int n_in,
                              void* d_out, int out_size, void* d_ws, size_t ws_size,
                              hipStream_t stream)
{
  const int*   ipr      = (const int*)d_in[0];
  const int*   isk      = (const int*)d_in[1];
  const float* embP     = (const float*)d_in[2];
  const float* embS     = (const float*)d_in[3];
  const float* mem_init = (const float*)d_in[4];
  const float* pos      = (const float*)d_in[5];
  const float* wqkv     = (const float*)d_in[6];
  const float* bqkv     = (const float*)d_in[7];
  const float* wo       = (const float*)d_in[8];
  const float* bo       = (const float*)d_in[9];
  const float* w1       = (const float*)d_in[10];
  const float* b1       = (const float*)d_in[11];
  const float* w2       = (const float*)d_in[12];
  const float* b2       = (const float*)d_in[13];
  const float* ln_a_g   = (const float*)d_in[14];
  const float* ln_a_b   = (const float*)d_in[15];
  const float* ln_f_g   = (const float*)d_in[16];
  const float* ln_f_b   = (const float*)d_in[17];
  const float* gw       = (const float*)d_in[18];
  const float* gb       = (const float*)d_in[19];
  float* out = (float*)d_out;
  (void)in_sizes; (void)n_in; (void)out_size; (void)ws_size;

  char* ws = (char*)d_ws;
  size_t off = 0;
  auto alloc = [&](size_t bytes) -> void* {
    void* p = ws + off; off += (bytes + 255) & ~(size_t)255; return p;
  };
  unsigned short* wqkv_b = (unsigned short*)alloc((size_t)3072 * 1024 * 2);
  unsigned short* wo_b   = (unsigned short*)alloc((size_t)1024 * 1024 * 2);
  unsigned short* w1_b   = (unsigned short*)alloc((size_t)4096 * 1024 * 2);
  unsigned short* w2_b   = (unsigned short*)alloc((size_t)1024 * 4096 * 2);
  unsigned short* gw_b   = (unsigned short*)alloc((size_t)1024 * 1024 * 2);
  float*          z      = (float*)alloc((size_t)B * T * D * 4);
  unsigned short* lnb    = (unsigned short*)alloc((size_t)B * T * D * 2);
  unsigned short* atno   = (unsigned short*)alloc((size_t)B * T * D * 2);
  unsigned short* big    = (unsigned short*)alloc((size_t)B * T * 4096 * 2); // qkv then ffn1
  unsigned short* candb  = (unsigned short*)alloc((size_t)B * MEM * D * 2);
  float*          memb   = (float*)alloc((size_t)B * MEM * D * 4);

  k_cvt<<<(3072 * 1024) / 256, 256, 0, stream>>>(wqkv, wqkv_b, 3072 * 1024);
  k_cvt<<<(1024 * 1024) / 256, 256, 0, stream>>>(wo,   wo_b,   1024 * 1024);
  k_cvt<<<(4096 * 1024) / 256, 256, 0, stream>>>(w1,   w1_b,   4096 * 1024);
  k_cvt<<<(1024 * 4096) / 256, 256, 0, stream>>>(w2,   w2_b,   1024 * 4096);
  k_cvt<<<(1024 * 1024) / 256, 256, 0, stream>>>(gw,   gw_b,   1024 * 1024);

  for (int t = 0; t < NC; ++t) {
    k_ln<0><<<B * T, 256, 0, stream>>>(memb, mem_init, pos, embP, embS, ipr, isk,
                                       ln_a_g, ln_a_b, z, lnb, t);
    { GArgs a{lnb, wqkv_b, bqkv, big, nullptr, nullptr, nullptr, nullptr, B * T, 3072, 1024, t};
      k_gemm3<0><<<dim3(3072 / 128, (B * T) / 256), 512, 0, stream>>>(a); }
    k_attn<<<B * H, 256, 0, stream>>>(big, atno);
    { GArgs a{atno, wo_b, bo, nullptr, z, nullptr, nullptr, nullptr, B * T, 1024, 1024, t};
      k_gemm3<2><<<dim3(1024 / 128, (B * T) / 256), 512, 0, stream>>>(a); }
    k_ln<1><<<B * T, 256, 0, stream>>>(nullptr, nullptr, nullptr, nullptr, nullptr,
                                       nullptr, nullptr, ln_f_g, ln_f_b, z, lnb, t);
    { GArgs a{lnb, w1_b, b1, big, nullptr, nullptr, nullptr, nullptr, B * T, 4096, 1024, t};
      k_gemm3<1><<<dim3(4096 / 128, (B * T) / 256), 512, 0, stream>>>(a); }
    { GArgs a{big, w2_b, b2, nullptr, z, out, candb, nullptr, B * T, 1024, 4096, t};
      k_gemm3<3><<<dim3(1024 / 128, (B * T) / 256), 512, 0, stream>>>(a); }
    { GArgs a{candb, gw_b, gb, nullptr, z, nullptr, nullptr, memb, B * MEM, 1024, 1024, t};
      k_gemm<4><<<dim3(1024 / 128, (B * MEM) / 128), 256, 0, stream>>>(a); }
  }
  k_copy_mem<<<(B * MEM * D) / 256, 256, 0, stream>>>(memb, out + (size_t)B * L * D);
}

// Round 4
// 6640.012 us; speedup vs baseline: 1.1142x; 1.0236x over previous
//
#include <hip/hip_runtime.h>
#include <cstdint>

typedef __attribute__((ext_vector_type(4))) float f32x4;
typedef __attribute__((ext_vector_type(8))) short s16x8;
typedef __attribute__((ext_vector_type(8))) unsigned short u16x8;
typedef __attribute__((ext_vector_type(4))) unsigned short u16x4;

#define DEVI __device__ __forceinline__

namespace {

constexpr int B = 32, L = 2048, D = 1024, H = 16;
constexpr int CHUNK = 128, MEM = 64, T = 192;
constexpr int NC = 16;

DEVI unsigned short f2bf(float f) {
  unsigned x = __builtin_bit_cast(unsigned, f);
  return (unsigned short)((x + 0x7fffu + ((x >> 16) & 1u)) >> 16);
}
DEVI float bf2f(unsigned short u) {
  return __builtin_bit_cast(float, (unsigned)u << 16);
}

typedef const __attribute__((address_space(1))) unsigned char ga_t;
typedef __attribute__((address_space(3))) unsigned char la_t;

DEVI void gload16(const void* g, void* l) {
  __builtin_amdgcn_global_load_lds((ga_t*)g, (la_t*)l, 16, 0, 0);
}

__global__ void k_cvt(const float* __restrict__ in, unsigned short* __restrict__ out, int n) {
  int i = blockIdx.x * 256 + threadIdx.x;
  if (i < n) out[i] = f2bf(in[i]);
}

__global__ void k_copy_mem(const float* __restrict__ src, float* __restrict__ dst) {
  int i = blockIdx.x * 256 + threadIdx.x;
  dst[i] = src[i];
}

// MODE 0: build z (mem/emb + pos), write z f32 and LN(z)->bf16 (all T rows)
// MODE 1: read z f32 (all T rows), write LN(z)->bf16
template<int MODE>
__global__ __launch_bounds__(256) void k_ln(
    const float* __restrict__ memb, const float* __restrict__ mem_init,
    const float* __restrict__ pos,
    const float* __restrict__ embP, const float* __restrict__ embS,
    const int* __restrict__ ipr, const int* __restrict__ isk,
    const float* __restrict__ gg, const float* __restrict__ bb,
    float* __restrict__ z, unsigned short* __restrict__ lnout, int t)
{
  const int row = blockIdx.x;          // 0 .. B*T-1
  const int b = row / T, i = row % T;
  const int tid = threadIdx.x;
  const int d0 = tid * 4;
  float v[4];
  if constexpr (MODE == 0) {
    if (i < MEM) {
      const float* src = (t == 0) ? (mem_init + (size_t)i * D)
                                  : (memb + ((size_t)b * MEM + i) * D);
      #pragma unroll
      for (int e = 0; e < 4; ++e) v[e] = src[d0 + e] + pos[i * D + d0 + e];
    } else {
      const int j = t * CHUNK + (i - MEM);
      const int pi = ipr[b * L + j], si = isk[b * L + j];
      #pragma unroll
      for (int e = 0; e < 4; ++e)
        v[e] = embP[(size_t)pi * D + d0 + e] + embS[(size_t)si * D + d0 + e] + pos[i * D + d0 + e];
    }
  } else {
    const f32x4 zz = *reinterpret_cast<const f32x4*>(&z[(size_t)row * D + d0]);
    v[0] = zz[0]; v[1] = zz[1]; v[2] = zz[2]; v[3] = zz[3];
  }
  float s  = v[0] + v[1] + v[2] + v[3];
  float s2 = v[0]*v[0] + v[1]*v[1] + v[2]*v[2] + v[3]*v[3];
  #pragma unroll
  for (int m = 1; m < 64; m <<= 1) { s += __shfl_xor(s, m, 64); s2 += __shfl_xor(s2, m, 64); }
  __shared__ float ps[4], ps2[4];
  const int wid = tid >> 6;
  if ((tid & 63) == 0) { ps[wid] = s; ps2[wid] = s2; }
  __syncthreads();
  s  = ps[0] + ps[1] + ps[2] + ps[3];
  s2 = ps2[0] + ps2[1] + ps2[2] + ps2[3];
  const float mu  = s * (1.0f / 1024.0f);
  const float var = s2 * (1.0f / 1024.0f) - mu * mu;
  const float rs  = rsqrtf(var + 1e-5f);
  if constexpr (MODE == 0) {
    f32x4 zz = {v[0], v[1], v[2], v[3]};
    *reinterpret_cast<f32x4*>(&z[(size_t)row * D + d0]) = zz;
  }
  u16x4 o;
  #pragma unroll
  for (int e = 0; e < 4; ++e)
    o[e] = f2bf((v[e] - mu) * rs * gg[d0 + e] + bb[d0 + e]);
  *reinterpret_cast<u16x4*>(&lnout[(size_t)row * D + d0]) = o;
}

// LN_f over mem rows only: row = b*64+i (grid B*MEM); reads z[(b*T+i)], compact out.
__global__ __launch_bounds__(256) void k_ln_mem(
    const float* __restrict__ z, const float* __restrict__ gg,
    const float* __restrict__ bb, unsigned short* __restrict__ lnout)
{
  const int row = blockIdx.x;
  const int b = row >> 6, i = row & 63;
  const int tid = threadIdx.x, d0 = tid * 4;
  const f32x4 zz = *reinterpret_cast<const f32x4*>(&z[((size_t)b * T + i) * D + d0]);
  float v[4] = {zz[0], zz[1], zz[2], zz[3]};
  float s  = v[0] + v[1] + v[2] + v[3];
  float s2 = v[0]*v[0] + v[1]*v[1] + v[2]*v[2] + v[3]*v[3];
  #pragma unroll
  for (int m = 1; m < 64; m <<= 1) { s += __shfl_xor(s, m, 64); s2 += __shfl_xor(s2, m, 64); }
  __shared__ float ps[4], ps2[4];
  const int wid = tid >> 6;
  if ((tid & 63) == 0) { ps[wid] = s; ps2[wid] = s2; }
  __syncthreads();
  s  = ps[0] + ps[1] + ps[2] + ps[3];
  s2 = ps2[0] + ps2[1] + ps2[2] + ps2[3];
  const float mu  = s * (1.0f / 1024.0f);
  const float var = s2 * (1.0f / 1024.0f) - mu * mu;
  const float rs  = rsqrtf(var + 1e-5f);
  u16x4 o;
  #pragma unroll
  for (int e = 0; e < 4; ++e)
    o[e] = f2bf((v[e] - mu) * rs * gg[d0 + e] + bb[d0 + e]);
  *reinterpret_cast<u16x4*>(&lnout[(size_t)row * D + d0]) = o;
}

// Deferred LN_f over bf16 rows of xc: global row = base + blockIdx.x, compact out.
__global__ __launch_bounds__(256) void k_ln_def(
    const unsigned short* __restrict__ xin, int base, const float* __restrict__ gg,
    const float* __restrict__ bb, unsigned short* __restrict__ lnout)
{
  const size_t row = (size_t)base + blockIdx.x;
  const int tid = threadIdx.x, d0 = tid * 4;
  const u16x4 xx = *reinterpret_cast<const u16x4*>(&xin[row * D + d0]);
  float v[4] = {bf2f(xx[0]), bf2f(xx[1]), bf2f(xx[2]), bf2f(xx[3])};
  float s  = v[0] + v[1] + v[2] + v[3];
  float s2 = v[0]*v[0] + v[1]*v[1] + v[2]*v[2] + v[3]*v[3];
  #pragma unroll
  for (int m = 1; m < 64; m <<= 1) { s += __shfl_xor(s, m, 64); s2 += __shfl_xor(s2, m, 64); }
  __shared__ float ps[4], ps2[4];
  const int wid = tid >> 6;
  if ((tid & 63) == 0) { ps[wid] = s; ps2[wid] = s2; }
  __syncthreads();
  s  = ps[0] + ps[1] + ps[2] + ps[3];
  s2 = ps2[0] + ps2[1] + ps2[2] + ps2[3];
  const float mu  = s * (1.0f / 1024.0f);
  const float var = s2 * (1.0f / 1024.0f) - mu * mu;
  const float rs  = rsqrtf(var + 1e-5f);
  u16x4 o;
  #pragma unroll
  for (int e = 0; e < 4; ++e)
    o[e] = f2bf((v[e] - mu) * rs * gg[d0 + e] + bb[d0 + e]);
  *reinterpret_cast<u16x4*>(&lnout[(size_t)blockIdx.x * D + d0]) = o;
}

struct GArgs {
  const unsigned short* A; const unsigned short* W; const float* bias;
  unsigned short* outb; float* z; float* outf; unsigned short* candb; float* mem;
  int M, N, K, t;
};

// C[M][N] = A[M][K] @ W[N][K]^T + bias. Proven m97-style 128x128 structure.
// EPI 0: bf16 out                 1: relu->bf16 out
// EPI 2: z += v (all rows)        3: fallback FFN2 (z&cand / d_out)
// EPI 4: sigmoid gate mem update
// EPI 5: WO split: mem rows z+=v; chunk rows xc(=outb) = bf16(z+v)
// EPI 6: FFN2_mem: z(b*T+i) += v; candb = bf16
// EPI 7: FFN2_big: outf[g] = bf2f(xc[g]) + v   (g = t + row; xc via candb ptr)
template<int EPI>
__global__ __launch_bounds__(256) void k_gemm(GArgs a)
{
  __shared__ unsigned short Al[128 * 64];
  __shared__ unsigned short Bl[128 * 64];
  const int tid = threadIdx.x;
  const int lane = tid & 63, wid = tid >> 6;
  const int brow = blockIdx.y * 128, bcol = blockIdx.x * 128;
  const int wr = wid >> 1, wc = wid & 1;
  const int lr = lane >> 3, lc8 = (lane & 7) * 8;
  const int c0 = lane & 15, g4 = lane >> 4;

  f32x4 acc[4][4] = {};

  const int nkt = a.K >> 6;
  for (int kt = 0; kt < nkt; ++kt) {
    const int kb = kt * 64;
    #pragma unroll
    for (int q = 0; q < 4; ++q) {
      const int seg = wid * 4 + q;
      gload16(&a.A[(size_t)(brow + seg * 8 + lr) * a.K + kb + lc8], &Al[seg * 512]);
      gload16(&a.W[(size_t)(bcol + seg * 8 + lr) * a.K + kb + lc8], &Bl[seg * 512]);
    }
    __syncthreads();
    #pragma unroll
    for (int kk = 0; kk < 2; ++kk) {
      s16x8 af[4], bf[4];
      #pragma unroll
      for (int m = 0; m < 4; ++m)
        af[m] = *reinterpret_cast<const s16x8*>(&Al[(wr * 64 + m * 16 + c0) * 64 + kk * 32 + g4 * 8]);
      #pragma unroll
      for (int n = 0; n < 4; ++n)
        bf[n] = *reinterpret_cast<const s16x8*>(&Bl[(wc * 64 + n * 16 + c0) * 64 + kk * 32 + g4 * 8]);
      #pragma unroll
      for (int m = 0; m < 4; ++m)
        #pragma unroll
        for (int n = 0; n < 4; ++n)
          acc[m][n] = __builtin_amdgcn_mfma_f32_16x16x32_bf16(af[m], bf[n], acc[m][n], 0, 0, 0);
    }
    __syncthreads();
  }

  #pragma unroll
  for (int m = 0; m < 4; ++m) {
    #pragma unroll
    for (int n = 0; n < 4; ++n) {
      const int col = bcol + wc * 64 + n * 16 + c0;
      const float bv = a.bias[col];
      #pragma unroll
      for (int j = 0; j < 4; ++j) {
        const int row = brow + wr * 64 + m * 16 + g4 * 4 + j;
        float v = acc[m][n][j] + bv;
        if constexpr (EPI == 0) {
          a.outb[(size_t)row * a.N + col] = f2bf(v);
        } else if constexpr (EPI == 1) {
          a.outb[(size_t)row * a.N + col] = f2bf(v > 0.f ? v : 0.f);
        } else if constexpr (EPI == 2) {
          a.z[(size_t)row * a.N + col] += v;
        } else if constexpr (EPI == 3) {
          const float zv = a.z[(size_t)row * a.N + col] + v;
          const int bb2 = row / T, ii = row % T;
          if (ii < MEM) {
            a.z[(size_t)row * a.N + col] = zv;
            a.candb[((size_t)bb2 * MEM + ii) * D + col] = f2bf(zv);
          } else {
            a.outf[((size_t)bb2 * L + a.t * CHUNK + (ii - MEM)) * D + col] = zv;
          }
        } else if constexpr (EPI == 4) {
          const float g = 1.0f / (1.0f + __expf(-v));
          const int bb2 = row >> 6, ii = row & 63;
          const float cand = a.z[((size_t)bb2 * T + ii) * D + col];
          const float mo = a.mem[(size_t)row * D + col];
          a.mem[(size_t)row * D + col] = (a.t == 0) ? cand : g * cand + (1.0f - g) * mo;
        } else if constexpr (EPI == 5) {
          const float zv = a.z[(size_t)row * a.N + col] + v;
          const int bb2 = row / T, ii = row % T;
          if (ii < MEM) {
            a.z[(size_t)row * a.N + col] = zv;
          } else {
            a.outb[((size_t)bb2 * L + a.t * CHUNK + (ii - MEM)) * D + col] = f2bf(zv);
          }
        } else if constexpr (EPI == 6) {
          const int bb2 = row >> 6, ii = row & 63;
          const size_t zi = ((size_t)bb2 * T + ii) * D + col;
          const float zv = a.z[zi] + v;
          a.z[zi] = zv;
          a.candb[(size_t)row * D + col] = f2bf(zv);
        } else {
          const size_t g = ((size_t)a.t + row) * D + col;
          a.outf[g] = bf2f(a.candb[g]) + v;
        }
      }
    }
  }
}

// One workgroup per (b,h). qkv: [B*T][3072] bf16 (q|k|v each H*64 cols).
__global__ __launch_bounds__(256) void k_attn(const unsigned short* __restrict__ qkv,
                                              unsigned short* __restrict__ attno)
{
  __shared__ unsigned short Ks[192 * 64];
  __shared__ unsigned short Vt[64 * 192];
  __shared__ unsigned short Pl[4][16 * 200];
  const int tid = threadIdx.x, lane = tid & 63, wid = tid >> 6;
  const int b = blockIdx.x >> 4, h = blockIdx.x & 15;
  const size_t base = (size_t)b * T * 3072 + h * 64;

  #pragma unroll
  for (int it = 0; it < 6; ++it) {
    const int cidx = tid + it * 256;
    const int key = cidx >> 3, hb = cidx & 7;
    const u16x8 kv = *reinterpret_cast<const u16x8*>(&qkv[base + (size_t)key * 3072 + 1024 + hb * 8]);
    *reinterpret_cast<u16x8*>(&Ks[key * 64 + ((hb ^ (key & 7)) * 8)]) = kv;
    const u16x8 vv = *reinterpret_cast<const u16x8*>(&qkv[base + (size_t)key * 3072 + 2048 + hb * 8]);
    #pragma unroll
    for (int e = 0; e < 8; ++e) {
      const int hd = hb * 8 + e;
      Vt[hd * 192 + (((key >> 3) + hd) % 24) * 8 + (key & 7)] = vv[e];
    }
  }
  __syncthreads();

  const int c0 = lane & 15, g4 = lane >> 4;
  for (int qb = wid; qb < 12; qb += 4) {
    s16x8 qf[2];
    #pragma unroll
    for (int kk = 0; kk < 2; ++kk)
      qf[kk] = *reinterpret_cast<const s16x8*>(&qkv[base + (size_t)(qb * 16 + c0) * 3072 + kk * 32 + g4 * 8]);
    f32x4 sc[12];
    #pragma unroll
    for (int cb = 0; cb < 12; ++cb) {
      f32x4 s4 = {};
      #pragma unroll
      for (int kk = 0; kk < 2; ++kk) {
        const s16x8 kf = *reinterpret_cast<const s16x8*>(
            &Ks[(cb * 16 + c0) * 64 + (((kk * 4 + g4) ^ (c0 & 7)) * 8)]);
        s4 = __builtin_amdgcn_mfma_f32_16x16x32_bf16(qf[kk], kf, s4, 0, 0, 0);
      }
      sc[cb] = s4;
    }
    #pragma unroll
    for (int j = 0; j < 4; ++j) {
      const int qi = qb * 16 + g4 * 4 + j;
      float mj = -1e30f;
      #pragma unroll
      for (int cb = 0; cb < 12; ++cb) {
        const int kj = cb * 16 + c0;
        float sv = sc[cb][j] * 0.125f;
        if (qi >= MEM && kj > qi) sv = -1e30f;
        sc[cb][j] = sv;
        mj = fmaxf(mj, sv);
      }
      #pragma unroll
      for (int msk = 1; msk <= 8; msk <<= 1) mj = fmaxf(mj, __shfl_xor(mj, msk, 64));
      float sum = 0.f;
      #pragma unroll
      for (int cb = 0; cb < 12; ++cb) {
        const float p = exp2f((sc[cb][j] - mj) * 1.44269504f);
        sc[cb][j] = p;
        sum += p;
      }
      #pragma unroll
      for (int msk = 1; msk <= 8; msk <<= 1) sum += __shfl_xor(sum, msk, 64);
      const float rin = 1.0f / sum;
      #pragma unroll
      for (int cb = 0; cb < 12; ++cb)
        Pl[wid][(g4 * 4 + j) * 200 + cb * 16 + c0] = f2bf(sc[cb][j] * rin);
    }
    #pragma unroll
    for (int cb2 = 0; cb2 < 4; ++cb2) {
      f32x4 ao = {};
      const int hd = cb2 * 16 + c0;
      #pragma unroll
      for (int kk = 0; kk < 6; ++kk) {
        const int k0 = kk * 32 + g4 * 8;
        const s16x8 pf = *reinterpret_cast<const s16x8*>(&Pl[wid][c0 * 200 + k0]);
        const s16x8 vf = *reinterpret_cast<const s16x8*>(&Vt[hd * 192 + (((k0 >> 3) + hd) % 24) * 8]);
        ao = __builtin_amdgcn_mfma_f32_16x16x32_bf16(pf, vf, ao, 0, 0, 0);
      }
      #pragma unroll
      for (int j = 0; j < 4; ++j) {
        const int q = qb * 16 + g4 * 4 + j;
        attno[((size_t)b * T + q) * D + h * 64 + cb2 * 16 + c0] = f2bf(ao[j]);
      }
    }
  }
}

} // namespace

extern "C" void kernel_launch(void* const* d_in, const int* in_sizes, int n_in,
                              void* d_out, int out_size, void* d_ws, size_t ws_size,
                              hipStream_t stream)
{
  const int*   ipr      = (const int*)d_in[0];
  const int*   isk      = (const int*)d_in[1];
  const float* embP     = (const float*)d_in[2];
  const float* embS     = (const float*)d_in[3];
  const float* mem_init = (const float*)d_in[4];
  const float* pos      = (const float*)d_in[5];
  const float* wqkv     = (const float*)d_in[6];
  const float* bqkv     = (const float*)d_in[7];
  const float* wo       = (const float*)d_in[8];
  const float* bo       = (const float*)d_in[9];
  const float* w1       = (const float*)d_in[10];
  const float* b1       = (const float*)d_in[11];
  const float* w2       = (const float*)d_in[12];
  const float* b2       = (const float*)d_in[13];
  const float* ln_a_g   = (const float*)d_in[14];
  const float* ln_a_b   = (const float*)d_in[15];
  const float* ln_f_g   = (const float*)d_in[16];
  const float* ln_f_b   = (const float*)d_in[17];
  const float* gw       = (const float*)d_in[18];
  const float* gb       = (const float*)d_in[19];
  float* out = (float*)d_out;
  (void)in_sizes; (void)n_in; (void)out_size;

  char* ws = (char*)d_ws;
  size_t off = 0;
  auto alloc = [&](size_t bytes) -> void* {
    void* p = ws + off; off += (bytes + 255) & ~(size_t)255; return p;
  };
  unsigned short* wqkv_b = (unsigned short*)alloc((size_t)3072 * 1024 * 2);
  unsigned short* wo_b   = (unsigned short*)alloc((size_t)1024 * 1024 * 2);
  unsigned short* w1_b   = (unsigned short*)alloc((size_t)4096 * 1024 * 2);
  unsigned short* w2_b   = (unsigned short*)alloc((size_t)1024 * 4096 * 2);
  unsigned short* gw_b   = (unsigned short*)alloc((size_t)1024 * 1024 * 2);
  float*          z      = (float*)alloc((size_t)B * T * D * 4);
  unsigned short* lnb    = (unsigned short*)alloc((size_t)B * T * D * 2);
  unsigned short* atno   = (unsigned short*)alloc((size_t)B * T * D * 2);
  unsigned short* big    = (unsigned short*)alloc((size_t)B * T * 4096 * 2); // qkv / ffn1_mem / lng
  unsigned short* candb  = (unsigned short*)alloc((size_t)B * MEM * D * 2);
  float*          memb   = (float*)alloc((size_t)B * MEM * D * 4);
  // deferred-path extras (allocated last so the fallback needs only the above)
  unsigned short* lnm    = (unsigned short*)alloc((size_t)B * MEM * D * 2);
  unsigned short* xc     = (unsigned short*)alloc((size_t)B * L * D * 2);       // 134 MB
  unsigned short* ffn1g  = (unsigned short*)alloc((size_t)8192 * 4096 * 2);     // 67 MB
  const bool deferred = (ws_size >= off);

  k_cvt<<<(3072 * 1024) / 256, 256, 0, stream>>>(wqkv, wqkv_b, 3072 * 1024);
  k_cvt<<<(1024 * 1024) / 256, 256, 0, stream>>>(wo,   wo_b,   1024 * 1024);
  k_cvt<<<(4096 * 1024) / 256, 256, 0, stream>>>(w1,   w1_b,   4096 * 1024);
  k_cvt<<<(1024 * 4096) / 256, 256, 0, stream>>>(w2,   w2_b,   1024 * 4096);
  k_cvt<<<(1024 * 1024) / 256, 256, 0, stream>>>(gw,   gw_b,   1024 * 1024);

  for (int t = 0; t < NC; ++t) {
    k_ln<0><<<B * T, 256, 0, stream>>>(memb, mem_init, pos, embP, embS, ipr, isk,
                                       ln_a_g, ln_a_b, z, lnb, t);
    { GArgs a{lnb, wqkv_b, bqkv, big, nullptr, nullptr, nullptr, nullptr, B * T, 3072, 1024, t};
      k_gemm<0><<<dim3(3072 / 128, (B * T) / 128), 256, 0, stream>>>(a); }
    k_attn<<<B * H, 256, 0, stream>>>(big, atno);
    if (deferred) {
      // WO: mem rows -> z; chunk rows -> xc (bf16 z-post-attention)
      { GArgs a{atno, wo_b, bo, xc, z, nullptr, nullptr, nullptr, B * T, 1024, 1024, t};
        k_gemm<5><<<dim3(1024 / 128, (B * T) / 128), 256, 0, stream>>>(a); }
      k_ln_mem<<<B * MEM, 256, 0, stream>>>(z, ln_f_g, ln_f_b, lnm);
      { GArgs a{lnm, w1_b, b1, big, nullptr, nullptr, nullptr, nullptr, B * MEM, 4096, 1024, t};
        k_gemm<1><<<dim3(4096 / 128, (B * MEM) / 128), 256, 0, stream>>>(a); }
      { GArgs a{big, w2_b, b2, nullptr, z, nullptr, candb, nullptr, B * MEM, 1024, 4096, t};
        k_gemm<6><<<dim3(1024 / 128, (B * MEM) / 128), 256, 0, stream>>>(a); }
    } else {
      { GArgs a{atno, wo_b, bo, nullptr, z, nullptr, nullptr, nullptr, B * T, 1024, 1024, t};
        k_gemm<2><<<dim3(1024 / 128, (B * T) / 128), 256, 0, stream>>>(a); }
      k_ln<1><<<B * T, 256, 0, stream>>>(nullptr, nullptr, nullptr, nullptr, nullptr,
                                         nullptr, nullptr, ln_f_g, ln_f_b, z, lnb, t);
      { GArgs a{lnb, w1_b, b1, big, nullptr, nullptr, nullptr, nullptr, B * T, 4096, 1024, t};
        k_gemm<1><<<dim3(4096 / 128, (B * T) / 128), 256, 0, stream>>>(a); }
      { GArgs a{big, w2_b, b2, nullptr, z, out, candb, nullptr, B * T, 1024, 4096, t};
        k_gemm<3><<<dim3(1024 / 128, (B * T) / 128), 256, 0, stream>>>(a); }
    }
    { GArgs a{candb, gw_b, gb, nullptr, z, nullptr, nullptr, memb, B * MEM, 1024, 1024, t};
      k_gemm<4><<<dim3(1024 / 128, (B * MEM) / 128), 256, 0, stream>>>(a); }
  }

  if (deferred) {
    // batched chunk-row output path: LN_f -> FFN1 -> FFN2 (+ residual from xc) -> d_out
    constexpr int RG = 8192;                 // rows per group
    for (int g = 0; g < (B * L) / RG; ++g) {
      k_ln_def<<<RG, 256, 0, stream>>>(xc, g * RG, ln_f_g, ln_f_b, big);
      { GArgs a{big, w1_b, b1, ffn1g, nullptr, nullptr, nullptr, nullptr, RG, 4096, 1024, 0};
        k_gemm<1><<<dim3(4096 / 128, RG / 128), 256, 0, stream>>>(a); }
      { GArgs a{ffn1g, w2_b, b2, nullptr, nullptr, out, xc, nullptr, RG, 1024, 4096, g * RG};
        k_gemm<7><<<dim3(1024 / 128, RG / 128), 256, 0, stream>>>(a); }
    }
  }
  k_copy_mem<<<(B * MEM * D) / 256, 256, 0, stream>>>(memb, out + (size_t)B * L * D);
}

// Round 5
// 6064.429 us; speedup vs baseline: 1.2199x; 1.0949x over previous
//
#include <hip/hip_runtime.h>
#include <cstdint>

typedef __attribute__((ext_vector_type(4))) float f32x4;
typedef __attribute__((ext_vector_type(8))) short s16x8;
typedef __attribute__((ext_vector_type(8))) unsigned short u16x8;
typedef __attribute__((ext_vector_type(4))) unsigned short u16x4;

#define DEVI __device__ __forceinline__

namespace {

constexpr int B = 32, L = 2048, D = 1024, H = 16;
constexpr int CHUNK = 128, MEM = 64, T = 192;
constexpr int NC = 16;

DEVI unsigned short f2bf(float f) {
  unsigned x = __builtin_bit_cast(unsigned, f);
  return (unsigned short)((x + 0x7fffu + ((x >> 16) & 1u)) >> 16);
}

typedef const __attribute__((address_space(1))) unsigned char ga_t;
typedef __attribute__((address_space(3))) unsigned char la_t;

DEVI void gload16(const void* g, void* l) {
  __builtin_amdgcn_global_load_lds((ga_t*)g, (la_t*)l, 16, 0, 0);
}

__global__ void k_cvt(const float* __restrict__ in, unsigned short* __restrict__ out, int n) {
  int i = blockIdx.x * 256 + threadIdx.x;
  if (i < n) out[i] = f2bf(in[i]);
}

__global__ void k_copy_mem(const float* __restrict__ src, float* __restrict__ dst) {
  int i = blockIdx.x * 256 + threadIdx.x;
  dst[i] = src[i];
}

// Wave-per-row LN: 4 rows per 256-thread block, no LDS, pure shuffle reduce.
// MODE 0: build z (mem/emb + pos), write z f32 and LN(z)->bf16
// MODE 1: read z f32, write LN(z)->bf16
template<int MODE>
__global__ __launch_bounds__(256) void k_lnw(
    const float* __restrict__ memb, const float* __restrict__ mem_init,
    const float* __restrict__ pos,
    const float* __restrict__ embP, const float* __restrict__ embS,
    const int* __restrict__ ipr, const int* __restrict__ isk,
    const float* __restrict__ gg, const float* __restrict__ bb,
    float* __restrict__ z, unsigned short* __restrict__ lnout, int t)
{
  const int tid = threadIdx.x, lane = tid & 63, wid = tid >> 6;
  const int row = blockIdx.x * 4 + wid;      // 0 .. B*T-1
  const int b = row / T, i = row % T;
  const int c0 = lane * 4;                   // lane's base col within each 256-chunk

  float v[16];
  if constexpr (MODE == 0) {
    if (i < MEM) {
      const float* src = (t == 0) ? (mem_init + (size_t)i * D)
                                  : (memb + ((size_t)b * MEM + i) * D);
      #pragma unroll
      for (int k = 0; k < 4; ++k) {
        const int c = k * 256 + c0;
        const f32x4 s = *reinterpret_cast<const f32x4*>(&src[c]);
        const f32x4 p = *reinterpret_cast<const f32x4*>(&pos[i * D + c]);
        #pragma unroll
        for (int e = 0; e < 4; ++e) v[k * 4 + e] = s[e] + p[e];
      }
    } else {
      const int j = t * CHUNK + (i - MEM);
      const int pi = ipr[b * L + j], si = isk[b * L + j];
      #pragma unroll
      for (int k = 0; k < 4; ++k) {
        const int c = k * 256 + c0;
        const f32x4 ep = *reinterpret_cast<const f32x4*>(&embP[(size_t)pi * D + c]);
        const f32x4 es = *reinterpret_cast<const f32x4*>(&embS[(size_t)si * D + c]);
        const f32x4 p  = *reinterpret_cast<const f32x4*>(&pos[i * D + c]);
        #pragma unroll
        for (int e = 0; e < 4; ++e) v[k * 4 + e] = ep[e] + es[e] + p[e];
      }
    }
  } else {
    #pragma unroll
    for (int k = 0; k < 4; ++k) {
      const f32x4 zz = *reinterpret_cast<const f32x4*>(&z[(size_t)row * D + k * 256 + c0]);
      #pragma unroll
      for (int e = 0; e < 4; ++e) v[k * 4 + e] = zz[e];
    }
  }
  float s = 0.f, s2 = 0.f;
  #pragma unroll
  for (int e = 0; e < 16; ++e) { s += v[e]; s2 += v[e] * v[e]; }
  #pragma unroll
  for (int m = 1; m < 64; m <<= 1) { s += __shfl_xor(s, m, 64); s2 += __shfl_xor(s2, m, 64); }
  const float mu  = s * (1.0f / 1024.0f);
  const float var = s2 * (1.0f / 1024.0f) - mu * mu;
  const float rs  = rsqrtf(var + 1e-5f);
  if constexpr (MODE == 0) {
    #pragma unroll
    for (int k = 0; k < 4; ++k) {
      f32x4 zz = {v[k*4+0], v[k*4+1], v[k*4+2], v[k*4+3]};
      *reinterpret_cast<f32x4*>(&z[(size_t)row * D + k * 256 + c0]) = zz;
    }
  }
  #pragma unroll
  for (int k = 0; k < 4; ++k) {
    const int c = k * 256 + c0;
    u16x4 o;
    #pragma unroll
    for (int e = 0; e < 4; ++e)
      o[e] = f2bf((v[k * 4 + e] - mu) * rs * gg[c + e] + bb[c + e]);
    *reinterpret_cast<u16x4*>(&lnout[(size_t)row * D + c]) = o;
  }
}

struct GArgs {
  const unsigned short* A; const unsigned short* W; const float* bias;
  unsigned short* outb; float* z; float* outf; unsigned short* candb; float* mem;
  int M, N, K, t;
};

// C[M][N] = A[M][K] @ W[N][K]^T + bias. Proven m97-style 128x128 structure,
// with T1 chunked-XCD tile swizzle (grid must be divisible by 8).
// EPI 0: bf16 out     1: relu->bf16 out    2: z += v
// EPI 3: zv=z+v; i<MEM -> z & cand_bf16 ; else -> d_out
// EPI 4: gate: mem = (t==0) ? cand : sig(v)*cand + (1-sig(v))*mem
template<int EPI>
__global__ __launch_bounds__(256) void k_gemm(GArgs a)
{
  __shared__ unsigned short Al[128 * 64];
  __shared__ unsigned short Bl[128 * 64];
  const int tid = threadIdx.x;
  const int lane = tid & 63, wid = tid >> 6;
  // T1: chunked XCD swizzle of the flat tile index (bijective when nwg%8==0)
  const int gx = gridDim.x;
  const int nwg = gx * gridDim.y;
  const int f = blockIdx.y * gx + blockIdx.x;
  const int tile = (f & 7) * (nwg >> 3) + (f >> 3);
  const int brow = (tile / gx) * 128, bcol = (tile % gx) * 128;
  const int wr = wid >> 1, wc = wid & 1;
  const int lr = lane >> 3, lc8 = (lane & 7) * 8;
  const int c0 = lane & 15, g4 = lane >> 4;

  f32x4 acc[4][4] = {};

  const int nkt = a.K >> 6;
  for (int kt = 0; kt < nkt; ++kt) {
    const int kb = kt * 64;
    #pragma unroll
    for (int q = 0; q < 4; ++q) {
      const int seg = wid * 4 + q;                       // 0..15, 8 rows each
      gload16(&a.A[(size_t)(brow + seg * 8 + lr) * a.K + kb + lc8], &Al[seg * 512]);
      gload16(&a.W[(size_t)(bcol + seg * 8 + lr) * a.K + kb + lc8], &Bl[seg * 512]);
    }
    __syncthreads();
    #pragma unroll
    for (int kk = 0; kk < 2; ++kk) {
      s16x8 af[4], bf[4];
      #pragma unroll
      for (int m = 0; m < 4; ++m)
        af[m] = *reinterpret_cast<const s16x8*>(&Al[(wr * 64 + m * 16 + c0) * 64 + kk * 32 + g4 * 8]);
      #pragma unroll
      for (int n = 0; n < 4; ++n)
        bf[n] = *reinterpret_cast<const s16x8*>(&Bl[(wc * 64 + n * 16 + c0) * 64 + kk * 32 + g4 * 8]);
      #pragma unroll
      for (int m = 0; m < 4; ++m)
        #pragma unroll
        for (int n = 0; n < 4; ++n)
          acc[m][n] = __builtin_amdgcn_mfma_f32_16x16x32_bf16(af[m], bf[n], acc[m][n], 0, 0, 0);
    }
    __syncthreads();
  }

  #pragma unroll
  for (int m = 0; m < 4; ++m) {
    #pragma unroll
    for (int n = 0; n < 4; ++n) {
      const int col = bcol + wc * 64 + n * 16 + c0;
      const float bv = a.bias[col];
      #pragma unroll
      for (int j = 0; j < 4; ++j) {
        const int row = brow + wr * 64 + m * 16 + g4 * 4 + j;
        float v = acc[m][n][j] + bv;
        if constexpr (EPI == 0) {
          a.outb[(size_t)row * a.N + col] = f2bf(v);
        } else if constexpr (EPI == 1) {
          a.outb[(size_t)row * a.N + col] = f2bf(v > 0.f ? v : 0.f);
        } else if constexpr (EPI == 2) {
          a.z[(size_t)row * a.N + col] += v;
        } else if constexpr (EPI == 3) {
          const float zv = a.z[(size_t)row * a.N + col] + v;
          const int bb2 = row / T, ii = row % T;
          if (ii < MEM) {
            a.z[(size_t)row * a.N + col] = zv;
            a.candb[((size_t)bb2 * MEM + ii) * D + col] = f2bf(zv);
          } else {
            a.outf[((size_t)bb2 * L + a.t * CHUNK + (ii - MEM)) * D + col] = zv;
          }
        } else {
          const float g = 1.0f / (1.0f + __expf(-v));
          const int bb2 = row >> 6, ii = row & 63;
          const float cand = a.z[((size_t)bb2 * T + ii) * D + col];
          const float mo = a.mem[(size_t)row * D + col];
          a.mem[(size_t)row * D + col] = (a.t == 0) ? cand : g * cand + (1.0f - g) * mo;
        }
      }
    }
  }
}

// One workgroup per (b,h). qkv: [B*T][3072] bf16 (q|k|v each H*64 cols).
__global__ __launch_bounds__(256) void k_attn(const unsigned short* __restrict__ qkv,
                                              unsigned short* __restrict__ attno)
{
  __shared__ unsigned short Ks[192 * 64];    // K, 8-elem-block XOR swizzle
  __shared__ unsigned short Vt[64 * 192];    // V^T, 8-key-block rotation per hd row
  __shared__ unsigned short Pl[4][16 * 200]; // per-wave P, padded rows
  const int tid = threadIdx.x, lane = tid & 63, wid = tid >> 6;
  const int b = blockIdx.x >> 4, h = blockIdx.x & 15;
  const size_t base = (size_t)b * T * 3072 + h * 64;

  #pragma unroll
  for (int it = 0; it < 6; ++it) {
    const int cidx = tid + it * 256;         // 0..1535 = 192 keys * 8 blocks
    const int key = cidx >> 3, hb = cidx & 7;
    const u16x8 kv = *reinterpret_cast<const u16x8*>(&qkv[base + (size_t)key * 3072 + 1024 + hb * 8]);
    *reinterpret_cast<u16x8*>(&Ks[key * 64 + ((hb ^ (key & 7)) * 8)]) = kv;
    const u16x8 vv = *reinterpret_cast<const u16x8*>(&qkv[base + (size_t)key * 3072 + 2048 + hb * 8]);
    #pragma unroll
    for (int e = 0; e < 8; ++e) {
      const int hd = hb * 8 + e;
      Vt[hd * 192 + (((key >> 3) + hd) % 24) * 8 + (key & 7)] = vv[e];
    }
  }
  __syncthreads();

  const int c0 = lane & 15, g4 = lane >> 4;
  for (int qb = wid; qb < 12; qb += 4) {     // 3 q-blocks per wave
    s16x8 qf[2];
    #pragma unroll
    for (int kk = 0; kk < 2; ++kk)
      qf[kk] = *reinterpret_cast<const s16x8*>(&qkv[base + (size_t)(qb * 16 + c0) * 3072 + kk * 32 + g4 * 8]);
    f32x4 sc[12];
    #pragma unroll
    for (int cb = 0; cb < 12; ++cb) {
      f32x4 s4 = {};
      #pragma unroll
      for (int kk = 0; kk < 2; ++kk) {
        const s16x8 kf = *reinterpret_cast<const s16x8*>(
            &Ks[(cb * 16 + c0) * 64 + (((kk * 4 + g4) ^ (c0 & 7)) * 8)]);
        s4 = __builtin_amdgcn_mfma_f32_16x16x32_bf16(qf[kk], kf, s4, 0, 0, 0);
      }
      sc[cb] = s4;
    }
    #pragma unroll
    for (int j = 0; j < 4; ++j) {
      const int qi = qb * 16 + g4 * 4 + j;
      float mj = -1e30f;
      #pragma unroll
      for (int cb = 0; cb < 12; ++cb) {
        const int kj = cb * 16 + c0;
        float sv = sc[cb][j] * 0.125f;
        if (qi >= MEM && kj > qi) sv = -1e30f;
        sc[cb][j] = sv;
        mj = fmaxf(mj, sv);
      }
      #pragma unroll
      for (int msk = 1; msk <= 8; msk <<= 1) mj = fmaxf(mj, __shfl_xor(mj, msk, 64));
      float sum = 0.f;
      #pragma unroll
      for (int cb = 0; cb < 12; ++cb) {
        const float p = exp2f((sc[cb][j] - mj) * 1.44269504f);
        sc[cb][j] = p;
        sum += p;
      }
      #pragma unroll
      for (int msk = 1; msk <= 8; msk <<= 1) sum += __shfl_xor(sum, msk, 64);
      const float rin = 1.0f / sum;
      #pragma unroll
      for (int cb = 0; cb < 12; ++cb)
        Pl[wid][(g4 * 4 + j) * 200 + cb * 16 + c0] = f2bf(sc[cb][j] * rin);
    }
    #pragma unroll
    for (int cb2 = 0; cb2 < 4; ++cb2) {
      f32x4 ao = {};
      const int hd = cb2 * 16 + c0;
      #pragma unroll
      for (int kk = 0; kk < 6; ++kk) {
        const int k0 = kk * 32 + g4 * 8;
        const s16x8 pf = *reinterpret_cast<const s16x8*>(&Pl[wid][c0 * 200 + k0]);
        const s16x8 vf = *reinterpret_cast<const s16x8*>(&Vt[hd * 192 + (((k0 >> 3) + hd) % 24) * 8]);
        ao = __builtin_amdgcn_mfma_f32_16x16x32_bf16(pf, vf, ao, 0, 0, 0);
      }
      #pragma unroll
      for (int j = 0; j < 4; ++j) {
        const int q = qb * 16 + g4 * 4 + j;
        attno[((size_t)b * T + q) * D + h * 64 + cb2 * 16 + c0] = f2bf(ao[j]);
      }
    }
  }
}

} // namespace

extern "C" void kernel_launch(void* const* d_in, const int* in_sizes, int n_in,
                              void* d_out, int out_size, void* d_ws, size_t ws_size,
                              hipStream_t stream)
{
  const int*   ipr      = (const int*)d_in[0];
  const int*   isk      = (const int*)d_in[1];
  const float* embP     = (const float*)d_in[2];
  const float* embS     = (const float*)d_in[3];
  const float* mem_init = (const float*)d_in[4];
  const float* pos      = (const float*)d_in[5];
  const float* wqkv     = (const float*)d_in[6];
  const float* bqkv     = (const float*)d_in[7];
  const float* wo       = (const float*)d_in[8];
  const float* bo       = (const float*)d_in[9];
  const float* w1       = (const float*)d_in[10];
  const float* b1       = (const float*)d_in[11];
  const float* w2       = (const float*)d_in[12];
  const float* b2       = (const float*)d_in[13];
  const float* ln_a_g   = (const float*)d_in[14];
  const float* ln_a_b   = (const float*)d_in[15];
  const float* ln_f_g   = (const float*)d_in[16];
  const float* ln_f_b   = (const float*)d_in[17];
  const float* gw       = (const float*)d_in[18];
  const float* gb       = (const float*)d_in[19];
  float* out = (float*)d_out;
  (void)in_sizes; (void)n_in; (void)out_size; (void)ws_size;

  char* ws = (char*)d_ws;
  size_t off = 0;
  auto alloc = [&](size_t bytes) -> void* {
    void* p = ws + off; off += (bytes + 255) & ~(size_t)255; return p;
  };
  unsigned short* wqkv_b = (unsigned short*)alloc((size_t)3072 * 1024 * 2);
  unsigned short* wo_b   = (unsigned short*)alloc((size_t)1024 * 1024 * 2);
  unsigned short* w1_b   = (unsigned short*)alloc((size_t)4096 * 1024 * 2);
  unsigned short* w2_b   = (unsigned short*)alloc((size_t)1024 * 4096 * 2);
  unsigned short* gw_b   = (unsigned short*)alloc((size_t)1024 * 1024 * 2);
  float*          z      = (float*)alloc((size_t)B * T * D * 4);
  unsigned short* lnb    = (unsigned short*)alloc((size_t)B * T * D * 2);
  unsigned short* atno   = (unsigned short*)alloc((size_t)B * T * D * 2);
  unsigned short* big    = (unsigned short*)alloc((size_t)B * T * 4096 * 2); // qkv then ffn1
  unsigned short* candb  = (unsigned short*)alloc((size_t)B * MEM * D * 2);
  float*          memb   = (float*)alloc((size_t)B * MEM * D * 4);

  k_cvt<<<(3072 * 1024) / 256, 256, 0, stream>>>(wqkv, wqkv_b, 3072 * 1024);
  k_cvt<<<(1024 * 1024) / 256, 256, 0, stream>>>(wo,   wo_b,   1024 * 1024);
  k_cvt<<<(4096 * 1024) / 256, 256, 0, stream>>>(w1,   w1_b,   4096 * 1024);
  k_cvt<<<(1024 * 4096) / 256, 256, 0, stream>>>(w2,   w2_b,   1024 * 4096);
  k_cvt<<<(1024 * 1024) / 256, 256, 0, stream>>>(gw,   gw_b,   1024 * 1024);

  for (int t = 0; t < NC; ++t) {
    k_lnw<0><<<(B * T) / 4, 256, 0, stream>>>(memb, mem_init, pos, embP, embS, ipr, isk,
                                              ln_a_g, ln_a_b, z, lnb, t);
    { GArgs a{lnb, wqkv_b, bqkv, big, nullptr, nullptr, nullptr, nullptr, B * T, 3072, 1024, t};
      k_gemm<0><<<dim3(3072 / 128, (B * T) / 128), 256, 0, stream>>>(a); }
    k_attn<<<B * H, 256, 0, stream>>>(big, atno);
    { GArgs a{atno, wo_b, bo, nullptr, z, nullptr, nullptr, nullptr, B * T, 1024, 1024, t};
      k_gemm<2><<<dim3(1024 / 128, (B * T) / 128), 256, 0, stream>>>(a); }
    k_lnw<1><<<(B * T) / 4, 256, 0, stream>>>(nullptr, nullptr, nullptr, nullptr, nullptr,
                                              nullptr, nullptr, ln_f_g, ln_f_b, z, lnb, t);
    { GArgs a{lnb, w1_b, b1, big, nullptr, nullptr, nullptr, nullptr, B * T, 4096, 1024, t};
      k_gemm<1><<<dim3(4096 / 128, (B * T) / 128), 256, 0, stream>>>(a); }
    { GArgs a{big, w2_b, b2, nullptr, z, out, candb, nullptr, B * T, 1024, 4096, t};
      k_gemm<3><<<dim3(1024 / 128, (B * T) / 128), 256, 0, stream>>>(a); }
    { GArgs a{candb, gw_b, gb, nullptr, z, nullptr, nullptr, memb, B * MEM, 1024, 1024, t};
      k_gemm<4><<<dim3(1024 / 128, (B * MEM) / 128), 256, 0, stream>>>(a); }
  }
  k_copy_mem<<<(B * MEM * D) / 256, 256, 0, stream>>>(memb, out + (size_t)B * L * D);
}

// Round 6
// 5389.669 us; speedup vs baseline: 1.3726x; 1.1252x over previous
//
#include <hip/hip_runtime.h>
#include <cstdint>

typedef __attribute__((ext_vector_type(4))) float f32x4;
typedef __attribute__((ext_vector_type(8))) short s16x8;
typedef __attribute__((ext_vector_type(8))) unsigned short u16x8;
typedef __attribute__((ext_vector_type(4))) unsigned short u16x4;

#define DEVI __device__ __forceinline__

namespace {

constexpr int B = 32, L = 2048, D = 1024, H = 16;
constexpr int CHUNK = 128, MEM = 64, T = 192;
constexpr int NC = 16;

DEVI unsigned short f2bf(float f) {
  unsigned x = __builtin_bit_cast(unsigned, f);
  return (unsigned short)((x + 0x7fffu + ((x >> 16) & 1u)) >> 16);
}

typedef const __attribute__((address_space(1))) unsigned char ga_t;
typedef __attribute__((address_space(3))) unsigned char la_t;

DEVI void gload16(const void* g, void* l) {
  __builtin_amdgcn_global_load_lds((ga_t*)g, (la_t*)l, 16, 0, 0);
}

__global__ void k_cvt(const float* __restrict__ in, unsigned short* __restrict__ out, int n) {
  int i = blockIdx.x * 256 + threadIdx.x;
  if (i < n) out[i] = f2bf(in[i]);
}

__global__ void k_copy_mem(const float* __restrict__ src, float* __restrict__ dst) {
  int i = blockIdx.x * 256 + threadIdx.x;
  dst[i] = src[i];
}

// Wave-per-row LN: 4 rows per 256-thread block, no LDS, pure shuffle reduce.
template<int MODE>
__global__ __launch_bounds__(256) void k_lnw(
    const float* __restrict__ memb, const float* __restrict__ mem_init,
    const float* __restrict__ pos,
    const float* __restrict__ embP, const float* __restrict__ embS,
    const int* __restrict__ ipr, const int* __restrict__ isk,
    const float* __restrict__ gg, const float* __restrict__ bb,
    float* __restrict__ z, unsigned short* __restrict__ lnout, int t)
{
  const int tid = threadIdx.x, lane = tid & 63, wid = tid >> 6;
  const int row = blockIdx.x * 4 + wid;      // 0 .. B*T-1
  const int b = row / T, i = row % T;
  const int c0 = lane * 4;

  float v[16];
  if constexpr (MODE == 0) {
    if (i < MEM) {
      const float* src = (t == 0) ? (mem_init + (size_t)i * D)
                                  : (memb + ((size_t)b * MEM + i) * D);
      #pragma unroll
      for (int k = 0; k < 4; ++k) {
        const int c = k * 256 + c0;
        const f32x4 s = *reinterpret_cast<const f32x4*>(&src[c]);
        const f32x4 p = *reinterpret_cast<const f32x4*>(&pos[i * D + c]);
        #pragma unroll
        for (int e = 0; e < 4; ++e) v[k * 4 + e] = s[e] + p[e];
      }
    } else {
      const int j = t * CHUNK + (i - MEM);
      const int pi = ipr[b * L + j], si = isk[b * L + j];
      #pragma unroll
      for (int k = 0; k < 4; ++k) {
        const int c = k * 256 + c0;
        const f32x4 ep = *reinterpret_cast<const f32x4*>(&embP[(size_t)pi * D + c]);
        const f32x4 es = *reinterpret_cast<const f32x4*>(&embS[(size_t)si * D + c]);
        const f32x4 p  = *reinterpret_cast<const f32x4*>(&pos[i * D + c]);
        #pragma unroll
        for (int e = 0; e < 4; ++e) v[k * 4 + e] = ep[e] + es[e] + p[e];
      }
    }
  } else {
    #pragma unroll
    for (int k = 0; k < 4; ++k) {
      const f32x4 zz = *reinterpret_cast<const f32x4*>(&z[(size_t)row * D + k * 256 + c0]);
      #pragma unroll
      for (int e = 0; e < 4; ++e) v[k * 4 + e] = zz[e];
    }
  }
  float s = 0.f, s2 = 0.f;
  #pragma unroll
  for (int e = 0; e < 16; ++e) { s += v[e]; s2 += v[e] * v[e]; }
  #pragma unroll
  for (int m = 1; m < 64; m <<= 1) { s += __shfl_xor(s, m, 64); s2 += __shfl_xor(s2, m, 64); }
  const float mu  = s * (1.0f / 1024.0f);
  const float var = s2 * (1.0f / 1024.0f) - mu * mu;
  const float rs  = rsqrtf(var + 1e-5f);
  if constexpr (MODE == 0) {
    #pragma unroll
    for (int k = 0; k < 4; ++k) {
      f32x4 zz = {v[k*4+0], v[k*4+1], v[k*4+2], v[k*4+3]};
      *reinterpret_cast<f32x4*>(&z[(size_t)row * D + k * 256 + c0]) = zz;
    }
  }
  #pragma unroll
  for (int k = 0; k < 4; ++k) {
    const int c = k * 256 + c0;
    u16x4 o;
    #pragma unroll
    for (int e = 0; e < 4; ++e)
      o[e] = f2bf((v[k * 4 + e] - mu) * rs * gg[c + e] + bb[c + e]);
    *reinterpret_cast<u16x4*>(&lnout[(size_t)row * D + c]) = o;
  }
}

struct GArgs {
  const unsigned short* A; const unsigned short* W; const float* bias;
  unsigned short* outb; float* z; float* outf; unsigned short* candb; float* mem;
  int M, N, K, t;
};

DEVI void epilogue_write(const GArgs& a, int EPI_row, float v, int row, int col, int N,
                         unsigned short* outb);

// ---- 2-phase double-buffered 128x128 GEMM (catalog T3-minimum recipe) ----
// Per K-tile (BK=32): { barrier [drains vmcnt -> buf[cur] certified];
//   stage(t+1) -> buf[cur^1]; 8 ds_read_b128 + 16 MFMA from buf[cur] }.
// One barrier per tile; loads hide under a full tile of compute; 32 KB LDS
// keeps baseline occupancy (~4 blocks/CU). T1 XCD swizzle on tiles.
// EPI 0: bf16 out   1: relu->bf16   2: z += v
// EPI 3: zv=z+v; i<MEM -> z & cand_bf16 ; else -> d_out
template<int EPI>
__global__ __launch_bounds__(256) void k_gemmp(GArgs a)
{
  __shared__ __align__(16) unsigned short Al[2][128 * 32];
  __shared__ __align__(16) unsigned short Bl[2][128 * 32];
  const int tid = threadIdx.x;
  const int lane = tid & 63, wid = tid >> 6;
  const int gx = gridDim.x;
  const int nwg = gx * gridDim.y;
  const int f = blockIdx.y * gx + blockIdx.x;
  const int tile = (f & 7) * (nwg >> 3) + (f >> 3);
  const int brow = (tile / gx) * 128, bcol = (tile % gx) * 128;
  const int wr = wid >> 1, wc = wid & 1;
  const int c0 = lane & 15, g4 = lane >> 4;
  const int K = a.K;

  // staging: position p in [0,512): row p>>2, 16B-octet p&3.
  // thread covers p = tid and p = tid + 256. Dest is linear: byte p*16.
  const int r0 = tid >> 2, oc8 = (tid & 3) * 8;
  const int dst0 = wid * 512, dst1 = 2048 + wid * 512;   // shorts

  f32x4 acc[4][4] = {};

  const unsigned short* __restrict__ Ag = a.A;
  const unsigned short* __restrict__ Wg = a.W;

  auto stage = [&](int t1, int buf) {
    const int kb = t1 * 32;
    gload16(&Ag[(size_t)(brow + r0) * K + kb + oc8],      &Al[buf][dst0]);
    gload16(&Ag[(size_t)(brow + 64 + r0) * K + kb + oc8], &Al[buf][dst1]);
    gload16(&Wg[(size_t)(bcol + r0) * K + kb + oc8],      &Bl[buf][dst0]);
    gload16(&Wg[(size_t)(bcol + 64 + r0) * K + kb + oc8], &Bl[buf][dst1]);
  };

  stage(0, 0);
  const int nt = K >> 5;
  int cur = 0;
  for (int t = 0; t < nt; ++t) {
    __syncthreads();                    // drains vmcnt: buf[cur] ready; buf[cur^1] free
    if (t + 1 < nt) stage(t + 1, cur ^ 1);
    s16x8 af[4], bf[4];
    #pragma unroll
    for (int m = 0; m < 4; ++m)
      af[m] = *reinterpret_cast<const s16x8*>(&Al[cur][(wr * 64 + m * 16 + c0) * 32 + g4 * 8]);
    #pragma unroll
    for (int n = 0; n < 4; ++n)
      bf[n] = *reinterpret_cast<const s16x8*>(&Bl[cur][(wc * 64 + n * 16 + c0) * 32 + g4 * 8]);
    #pragma unroll
    for (int m = 0; m < 4; ++m)
      #pragma unroll
      for (int n = 0; n < 4; ++n)
        acc[m][n] = __builtin_amdgcn_mfma_f32_16x16x32_bf16(af[m], bf[n], acc[m][n], 0, 0, 0);
    cur ^= 1;
  }

  #pragma unroll
  for (int m = 0; m < 4; ++m) {
    #pragma unroll
    for (int n = 0; n < 4; ++n) {
      const int col = bcol + wc * 64 + n * 16 + c0;
      const float bv = a.bias[col];
      #pragma unroll
      for (int j = 0; j < 4; ++j) {
        const int row = brow + wr * 64 + m * 16 + g4 * 4 + j;
        float v = acc[m][n][j] + bv;
        if constexpr (EPI == 0) {
          a.outb[(size_t)row * a.N + col] = f2bf(v);
        } else if constexpr (EPI == 1) {
          a.outb[(size_t)row * a.N + col] = f2bf(v > 0.f ? v : 0.f);
        } else if constexpr (EPI == 2) {
          a.z[(size_t)row * a.N + col] += v;
        } else if constexpr (EPI == 3) {
          const float zv = a.z[(size_t)row * a.N + col] + v;
          const int bb2 = row / T, ii = row % T;
          if (ii < MEM) {
            a.z[(size_t)row * a.N + col] = zv;
            a.candb[((size_t)bb2 * MEM + ii) * D + col] = f2bf(zv);
          } else {
            a.outf[((size_t)bb2 * L + a.t * CHUNK + (ii - MEM)) * D + col] = zv;
          }
        }
      }
    }
  }
}

// ---- legacy 128x128 kernel (kept for the small gate GEMM) ----
template<int EPI>
__global__ __launch_bounds__(256) void k_gemm(GArgs a)
{
  __shared__ unsigned short Al[128 * 64];
  __shared__ unsigned short Bl[128 * 64];
  const int tid = threadIdx.x;
  const int lane = tid & 63, wid = tid >> 6;
  const int gx = gridDim.x;
  const int nwg = gx * gridDim.y;
  const int f = blockIdx.y * gx + blockIdx.x;
  const int tile = (f & 7) * (nwg >> 3) + (f >> 3);
  const int brow = (tile / gx) * 128, bcol = (tile % gx) * 128;
  const int wr = wid >> 1, wc = wid & 1;
  const int lr = lane >> 3, lc8 = (lane & 7) * 8;
  const int c0 = lane & 15, g4 = lane >> 4;

  f32x4 acc[4][4] = {};

  const int nkt = a.K >> 6;
  for (int kt = 0; kt < nkt; ++kt) {
    const int kb = kt * 64;
    #pragma unroll
    for (int q = 0; q < 4; ++q) {
      const int seg = wid * 4 + q;
      gload16(&a.A[(size_t)(brow + seg * 8 + lr) * a.K + kb + lc8], &Al[seg * 512]);
      gload16(&a.W[(size_t)(bcol + seg * 8 + lr) * a.K + kb + lc8], &Bl[seg * 512]);
    }
    __syncthreads();
    #pragma unroll
    for (int kk = 0; kk < 2; ++kk) {
      s16x8 af[4], bf[4];
      #pragma unroll
      for (int m = 0; m < 4; ++m)
        af[m] = *reinterpret_cast<const s16x8*>(&Al[(wr * 64 + m * 16 + c0) * 64 + kk * 32 + g4 * 8]);
      #pragma unroll
      for (int n = 0; n < 4; ++n)
        bf[n] = *reinterpret_cast<const s16x8*>(&Bl[(wc * 64 + n * 16 + c0) * 64 + kk * 32 + g4 * 8]);
      #pragma unroll
      for (int m = 0; m < 4; ++m)
        #pragma unroll
        for (int n = 0; n < 4; ++n)
          acc[m][n] = __builtin_amdgcn_mfma_f32_16x16x32_bf16(af[m], bf[n], acc[m][n], 0, 0, 0);
    }
    __syncthreads();
  }

  #pragma unroll
  for (int m = 0; m < 4; ++m) {
    #pragma unroll
    for (int n = 0; n < 4; ++n) {
      const int col = bcol + wc * 64 + n * 16 + c0;
      const float bv = a.bias[col];
      #pragma unroll
      for (int j = 0; j < 4; ++j) {
        const int row = brow + wr * 64 + m * 16 + g4 * 4 + j;
        float v = acc[m][n][j] + bv;
        if constexpr (EPI == 4) {
          const float g = 1.0f / (1.0f + __expf(-v));
          const int bb2 = row >> 6, ii = row & 63;
          const float cand = a.z[((size_t)bb2 * T + ii) * D + col];
          const float mo = a.mem[(size_t)row * D + col];
          a.mem[(size_t)row * D + col] = (a.t == 0) ? cand : g * cand + (1.0f - g) * mo;
        }
      }
    }
  }
}

// One workgroup per (b,h). qkv: [B*T][3072] bf16 (q|k|v each H*64 cols).
__global__ __launch_bounds__(256) void k_attn(const unsigned short* __restrict__ qkv,
                                              unsigned short* __restrict__ attno)
{
  __shared__ unsigned short Ks[192 * 64];
  __shared__ unsigned short Vt[64 * 192];
  __shared__ unsigned short Pl[4][16 * 200];
  const int tid = threadIdx.x, lane = tid & 63, wid = tid >> 6;
  const int b = blockIdx.x >> 4, h = blockIdx.x & 15;
  const size_t base = (size_t)b * T * 3072 + h * 64;

  #pragma unroll
  for (int it = 0; it < 6; ++it) {
    const int cidx = tid + it * 256;
    const int key = cidx >> 3, hb = cidx & 7;
    const u16x8 kv = *reinterpret_cast<const u16x8*>(&qkv[base + (size_t)key * 3072 + 1024 + hb * 8]);
    *reinterpret_cast<u16x8*>(&Ks[key * 64 + ((hb ^ (key & 7)) * 8)]) = kv;
    const u16x8 vv = *reinterpret_cast<const u16x8*>(&qkv[base + (size_t)key * 3072 + 2048 + hb * 8]);
    #pragma unroll
    for (int e = 0; e < 8; ++e) {
      const int hd = hb * 8 + e;
      Vt[hd * 192 + (((key >> 3) + hd) % 24) * 8 + (key & 7)] = vv[e];
    }
  }
  __syncthreads();

  const int c0 = lane & 15, g4 = lane >> 4;
  for (int qb = wid; qb < 12; qb += 4) {
    s16x8 qf[2];
    #pragma unroll
    for (int kk = 0; kk < 2; ++kk)
      qf[kk] = *reinterpret_cast<const s16x8*>(&qkv[base + (size_t)(qb * 16 + c0) * 3072 + kk * 32 + g4 * 8]);
    f32x4 sc[12];
    #pragma unroll
    for (int cb = 0; cb < 12; ++cb) {
      f32x4 s4 = {};
      #pragma unroll
      for (int kk = 0; kk < 2; ++kk) {
        const s16x8 kf = *reinterpret_cast<const s16x8*>(
            &Ks[(cb * 16 + c0) * 64 + (((kk * 4 + g4) ^ (c0 & 7)) * 8)]);
        s4 = __builtin_amdgcn_mfma_f32_16x16x32_bf16(qf[kk], kf, s4, 0, 0, 0);
      }
      sc[cb] = s4;
    }
    #pragma unroll
    for (int j = 0; j < 4; ++j) {
      const int qi = qb * 16 + g4 * 4 + j;
      float mj = -1e30f;
      #pragma unroll
      for (int cb = 0; cb < 12; ++cb) {
        const int kj = cb * 16 + c0;
        float sv = sc[cb][j] * 0.125f;
        if (qi >= MEM && kj > qi) sv = -1e30f;
        sc[cb][j] = sv;
        mj = fmaxf(mj, sv);
      }
      #pragma unroll
      for (int msk = 1; msk <= 8; msk <<= 1) mj = fmaxf(mj, __shfl_xor(mj, msk, 64));
      float sum = 0.f;
      #pragma unroll
      for (int cb = 0; cb < 12; ++cb) {
        const float p = exp2f((sc[cb][j] - mj) * 1.44269504f);
        sc[cb][j] = p;
        sum += p;
      }
      #pragma unroll
      for (int msk = 1; msk <= 8; msk <<= 1) sum += __shfl_xor(sum, msk, 64);
      const float rin = 1.0f / sum;
      #pragma unroll
      for (int cb = 0; cb < 12; ++cb)
        Pl[wid][(g4 * 4 + j) * 200 + cb * 16 + c0] = f2bf(sc[cb][j] * rin);
    }
    #pragma unroll
    for (int cb2 = 0; cb2 < 4; ++cb2) {
      f32x4 ao = {};
      const int hd = cb2 * 16 + c0;
      #pragma unroll
      for (int kk = 0; kk < 6; ++kk) {
        const int k0 = kk * 32 + g4 * 8;
        const s16x8 pf = *reinterpret_cast<const s16x8*>(&Pl[wid][c0 * 200 + k0]);
        const s16x8 vf = *reinterpret_cast<const s16x8*>(&Vt[hd * 192 + (((k0 >> 3) + hd) % 24) * 8]);
        ao = __builtin_amdgcn_mfma_f32_16x16x32_bf16(pf, vf, ao, 0, 0, 0);
      }
      #pragma unroll
      for (int j = 0; j < 4; ++j) {
        const int q = qb * 16 + g4 * 4 + j;
        attno[((size_t)b * T + q) * D + h * 64 + cb2 * 16 + c0] = f2bf(ao[j]);
      }
    }
  }
}

} // namespace

extern "C" void kernel_launch(void* const* d_in, const int* in_sizes, int n_in,
                              void* d_out, int out_size, void* d_ws, size_t ws_size,
                              hipStream_t stream)
{
  const int*   ipr      = (const int*)d_in[0];
  const int*   isk      = (const int*)d_in[1];
  const float* embP     = (const float*)d_in[2];
  const float* embS     = (const float*)d_in[3];
  const float* mem_init = (const float*)d_in[4];
  const float* pos      = (const float*)d_in[5];
  const float* wqkv     = (const float*)d_in[6];
  const float* bqkv     = (const float*)d_in[7];
  const float* wo       = (const float*)d_in[8];
  const float* bo       = (const float*)d_in[9];
  const float* w1       = (const float*)d_in[10];
  const float* b1       = (const float*)d_in[11];
  const float* w2       = (const float*)d_in[12];
  const float* b2       = (const float*)d_in[13];
  const float* ln_a_g   = (const float*)d_in[14];
  const float* ln_a_b   = (const float*)d_in[15];
  const float* ln_f_g   = (const float*)d_in[16];
  const float* ln_f_b   = (const float*)d_in[17];
  const float* gw       = (const float*)d_in[18];
  const float* gb       = (const float*)d_in[19];
  float* out = (float*)d_out;
  (void)in_sizes; (void)n_in; (void)out_size; (void)ws_size;

  char* ws = (char*)d_ws;
  size_t off = 0;
  auto alloc = [&](size_t bytes) -> void* {
    void* p = ws + off; off += (bytes + 255) & ~(size_t)255; return p;
  };
  unsigned short* wqkv_b = (unsigned short*)alloc((size_t)3072 * 1024 * 2);
  unsigned short* wo_b   = (unsigned short*)alloc((size_t)1024 * 1024 * 2);
  unsigned short* w1_b   = (unsigned short*)alloc((size_t)4096 * 1024 * 2);
  unsigned short* w2_b   = (unsigned short*)alloc((size_t)1024 * 4096 * 2);
  unsigned short* gw_b   = (unsigned short*)alloc((size_t)1024 * 1024 * 2);
  float*          z      = (float*)alloc((size_t)B * T * D * 4);
  unsigned short* lnb    = (unsigned short*)alloc((size_t)B * T * D * 2);
  unsigned short* atno   = (unsigned short*)alloc((size_t)B * T * D * 2);
  unsigned short* big    = (unsigned short*)alloc((size_t)B * T * 4096 * 2); // qkv then ffn1
  unsigned short* candb  = (unsigned short*)alloc((size_t)B * MEM * D * 2);
  float*          memb   = (float*)alloc((size_t)B * MEM * D * 4);

  k_cvt<<<(3072 * 1024) / 256, 256, 0, stream>>>(wqkv, wqkv_b, 3072 * 1024);
  k_cvt<<<(1024 * 1024) / 256, 256, 0, stream>>>(wo,   wo_b,   1024 * 1024);
  k_cvt<<<(4096 * 1024) / 256, 256, 0, stream>>>(w1,   w1_b,   4096 * 1024);
  k_cvt<<<(1024 * 4096) / 256, 256, 0, stream>>>(w2,   w2_b,   1024 * 4096);
  k_cvt<<<(1024 * 1024) / 256, 256, 0, stream>>>(gw,   gw_b,   1024 * 1024);

  for (int t = 0; t < NC; ++t) {
    k_lnw<0><<<(B * T) / 4, 256, 0, stream>>>(memb, mem_init, pos, embP, embS, ipr, isk,
                                              ln_a_g, ln_a_b, z, lnb, t);
    { GArgs a{lnb, wqkv_b, bqkv, big, nullptr, nullptr, nullptr, nullptr, B * T, 3072, 1024, t};
      k_gemmp<0><<<dim3(3072 / 128, (B * T) / 128), 256, 0, stream>>>(a); }
    k_attn<<<B * H, 256, 0, stream>>>(big, atno);
    { GArgs a{atno, wo_b, bo, nullptr, z, nullptr, nullptr, nullptr, B * T, 1024, 1024, t};
      k_gemmp<2><<<dim3(1024 / 128, (B * T) / 128), 256, 0, stream>>>(a); }
    k_lnw<1><<<(B * T) / 4, 256, 0, stream>>>(nullptr, nullptr, nullptr, nullptr, nullptr,
                                              nullptr, nullptr, ln_f_g, ln_f_b, z, lnb, t);
    { GArgs a{lnb, w1_b, b1, big, nullptr, nullptr, nullptr, nullptr, B * T, 4096, 1024, t};
      k_gemmp<1><<<dim3(4096 / 128, (B * T) / 128), 256, 0, stream>>>(a); }
    { GArgs a{big, w2_b, b2, nullptr, z, out, candb, nullptr, B * T, 1024, 4096, t};
      k_gemmp<3><<<dim3(1024 / 128, (B * T) / 128), 256, 0, stream>>>(a); }
    { GArgs a{candb, gw_b, gb, nullptr, z, nullptr, nullptr, memb, B * MEM, 1024, 1024, t};
      k_gemm<4><<<dim3(1024 / 128, (B * MEM) / 128), 256, 0, stream>>>(a); }
  }
  k_copy_mem<<<(B * MEM * D) / 256, 256, 0, stream>>>(memb, out + (size_t)B * L * D);
}